// Round 1
// baseline (5762.921 us; speedup 1.0000x reference)
//
#include <hip/hip_runtime.h>
#include <cstdint>

#define HID 128
#define NHEAD 4
#define HDIM 32
#define NGRAPH 64
#define MM_ROWS 16

// ---------------- projection: out[N,128] = x[N,K] @ Wp[K,128] + bp ----------------
__global__ void k_proj(const float* __restrict__ x, const float* __restrict__ Wp,
                       const float* __restrict__ bp, float* __restrict__ out,
                       int N, int K) {
    int idx = blockIdx.x * blockDim.x + threadIdx.x;
    if (idx >= N * HID) return;
    int row = idx >> 7, c = idx & 127;
    float acc = bp[c];
    for (int k = 0; k < K; ++k) acc += x[row * K + k] * Wp[k * HID + c];
    out[idx] = acc;
}

// ---------------- hs[N,128] = A[N,128] @ W[128,128] ----------------
__global__ void k_matmul(const float* __restrict__ A, const float* __restrict__ W,
                         float* __restrict__ out, int N) {
    __shared__ float As[MM_ROWS][HID];
    int r0 = blockIdx.x * MM_ROWS;
    int t = threadIdx.x; // 256 threads
    for (int i = t; i < MM_ROWS * HID; i += 256) {
        int r = i >> 7;
        As[r][i & 127] = (r0 + r < N) ? A[(size_t)(r0 + r) * HID + (i & 127)] : 0.f;
    }
    __syncthreads();
    int c = t & 127;
    int rbase = (t >> 7) * (MM_ROWS / 2); // 8 rows per thread
    float acc[MM_ROWS / 2];
#pragma unroll
    for (int r = 0; r < MM_ROWS / 2; ++r) acc[r] = 0.f;
    for (int k = 0; k < HID; ++k) {
        float w = W[k * HID + c];
#pragma unroll
        for (int r = 0; r < MM_ROWS / 2; ++r) acc[r] += As[rbase + r][k] * w;
    }
#pragma unroll
    for (int r = 0; r < MM_ROWS / 2; ++r) {
        int row = r0 + rbase + r;
        if (row < N) out[(size_t)row * HID + c] = acc[r];
    }
}

// ---------------- al_s[i,h] = sum_d hs[i,h*32+d] * a_s[h*32+d] ----------------
__global__ void k_als(const float* __restrict__ hs, const float* __restrict__ a_s,
                      float* __restrict__ als, int N) {
    __shared__ float as_s[HID];
    int t = threadIdx.x;
    if (t < HID) as_s[t] = a_s[t];
    __syncthreads();
    int idx = blockIdx.x * blockDim.x + t;
    if (idx >= N * NHEAD) return;
    int i = idx >> 2, h = idx & 3;
    const float* p = hs + (size_t)i * HID + h * HDIM;
    const float* a = as_s + h * HDIM;
    float s = 0.f;
#pragma unroll
    for (int j = 0; j < HDIM; ++j) s += p[j] * a[j];
    als[idx] = s;
}

// ---------------- vd[k,h] = sum_j W[k, h*32+j] * a_d[h*32+j] ----------------
__global__ void k_vd(const float* __restrict__ W, const float* __restrict__ a_d,
                     float* __restrict__ vd) {
    int idx = blockIdx.x * blockDim.x + threadIdx.x;
    if (idx >= HID * NHEAD) return;
    int k = idx >> 2, h = idx & 3;
    float s = 0.f;
#pragma unroll
    for (int j = 0; j < HDIM; ++j) s += W[k * HID + h * HDIM + j] * a_d[h * HDIM + j];
    vd[idx] = s;
}

// ---------------- al_d[i,h] = sum_k x[i,k] * vd[k,h] ----------------
__global__ void k_ald(const float* __restrict__ x, const float* __restrict__ vd,
                      float* __restrict__ ald, int N) {
    __shared__ float vs[HID * NHEAD];
    int t = threadIdx.x;
    for (int i = t; i < HID * NHEAD; i += blockDim.x) vs[i] = vd[i];
    __syncthreads();
    int idx = blockIdx.x * blockDim.x + t;
    if (idx >= N * NHEAD) return;
    int i = idx >> 2, h = idx & 3;
    const float* row = x + (size_t)i * HID;
    float s = 0.f;
#pragma unroll 8
    for (int k = 0; k < HID; ++k) s += row[k] * vs[k * NHEAD + h];
    ald[idx] = s;
}

// ---------------- edge pass A: ex = exp(leaky_relu(al_s[src]+al_d[dst])), den += ex ----------------
__global__ void k_edgeA(const int* __restrict__ src, const int* __restrict__ dst,
                        const float* __restrict__ als, const float* __restrict__ ald,
                        float* __restrict__ ex, float* __restrict__ den, int E) {
    int idx = blockIdx.x * blockDim.x + threadIdx.x;
    if (idx >= E * NHEAD) return;
    int e = idx >> 2, h = idx & 3;
    int s = src[e], d = dst[e];
    float a = als[s * NHEAD + h] + ald[d * NHEAD + h];
    a = (a > 0.f) ? a : 0.2f * a;
    float v = __expf(a);
    ex[idx] = v;
    atomicAdd(&den[d * NHEAD + h], v);
}

// ---------------- edge pass B: acc[dst, c] += hs[src, c] * ex/(den+eps) ----------------
__global__ void k_edgeB(const int* __restrict__ src, const int* __restrict__ dst,
                        const float* __restrict__ hs, const float* __restrict__ ex,
                        const float* __restrict__ den, float* __restrict__ acc, int E) {
    int idx = blockIdx.x * blockDim.x + threadIdx.x;
    if (idx >= E * HID) return;
    int e = idx >> 7, c = idx & 127, h = c >> 5;
    int s = src[e], d = dst[e];
    float coef = ex[e * NHEAD + h] / (den[d * NHEAD + h] + 1e-16f);
    atomicAdd(&acc[(size_t)d * HID + c], hs[(size_t)s * HID + c] * coef);
}

// ---------------- bias_sum[t,c] = sum over relations targeting type t of gat_b[l,r,c] ----------------
__global__ void k_biassum(const float* __restrict__ gat_b_layer, float* __restrict__ bias_sum) {
    int idx = blockIdx.x * blockDim.x + threadIdx.x;
    if (idx >= 4 * HID) return;
    int t = idx >> 7, c = idx & 127;
    const int rels[4][3] = {{1, 3, 5}, {0, -1, -1}, {2, -1, -1}, {4, 6, 7}};
    float s = 0.f;
#pragma unroll
    for (int j = 0; j < 3; ++j) {
        int r = rels[t][j];
        if (r >= 0) s += gat_b_layer[r * HID + c];
    }
    bias_sum[idx] = s;
}

// ---------------- finalize: x = LN(relu((acc+bias_sum)*cnt_inv) + x) ----------------
__global__ void k_finalize(float* __restrict__ x, const float* __restrict__ acc,
                           const float* __restrict__ bias_sum, float cnt_inv,
                           const float* __restrict__ ln_s, const float* __restrict__ ln_b,
                           int N) {
    int gwave = (blockIdx.x * blockDim.x + threadIdx.x) >> 6;
    int lane = threadIdx.x & 63;
    if (gwave >= N) return;
    float y[2];
    float s = 0.f, ss = 0.f;
#pragma unroll
    for (int i = 0; i < 2; ++i) {
        int c = i * 64 + lane; // coalesced
        float v = (acc[(size_t)gwave * HID + c] + bias_sum[c]) * cnt_inv;
        v = v > 0.f ? v : 0.f;
        v += x[(size_t)gwave * HID + c];
        y[i] = v;
        s += v;
        ss += v * v;
    }
#pragma unroll
    for (int off = 32; off; off >>= 1) {
        s += __shfl_down(s, off);
        ss += __shfl_down(ss, off);
    }
    s = __shfl(s, 0);
    ss = __shfl(ss, 0);
    float mu = s * (1.f / HID);
    float var = ss * (1.f / HID) - mu * mu;
    float rstd = rsqrtf(var + 1e-5f);
#pragma unroll
    for (int i = 0; i < 2; ++i) {
        int c = i * 64 + lane;
        x[(size_t)gwave * HID + c] = (y[i] - mu) * rstd * ln_s[c] + ln_b[c];
    }
}

// ---------------- pooling ----------------
__global__ void k_pool_accum(const float* __restrict__ x, const int* __restrict__ bidx,
                             float* __restrict__ out, int N, int col_off) {
    int idx = blockIdx.x * blockDim.x + threadIdx.x;
    if (idx >= N * HID) return;
    int i = idx >> 7, c = idx & 127;
    int g = bidx[i];
    atomicAdd(&out[g * 512 + col_off + c], x[(size_t)i * HID + c]);
}

__global__ void k_count(const int* __restrict__ bidx, float* __restrict__ cnt, int N, int toff) {
    int i = blockIdx.x * blockDim.x + threadIdx.x;
    if (i >= N) return;
    atomicAdd(&cnt[toff + bidx[i]], 1.0f);
}

__global__ void k_pool_div(float* __restrict__ out, const float* __restrict__ cnt) {
    int idx = blockIdx.x * blockDim.x + threadIdx.x;
    if (idx >= NGRAPH * 512) return;
    int g = idx >> 9, c = idx & 511;
    int t = c >> 7;
    float cc = cnt[t * NGRAPH + g];
    out[idx] = out[idx] / fmaxf(cc, 1.0f);
}

extern "C" void kernel_launch(void* const* d_in, const int* in_sizes, int n_in,
                              void* d_out, int out_size, void* d_ws, size_t ws_size,
                              hipStream_t stream) {
    const float* x_in[4] = {(const float*)d_in[0], (const float*)d_in[1],
                            (const float*)d_in[2], (const float*)d_in[3]};
    const float* Wp[4] = {(const float*)d_in[4], (const float*)d_in[6],
                          (const float*)d_in[8], (const float*)d_in[10]};
    const float* bp[4] = {(const float*)d_in[5], (const float*)d_in[7],
                          (const float*)d_in[9], (const float*)d_in[11]};
    const float* gat_W  = (const float*)d_in[12];
    const float* gat_as = (const float*)d_in[13];
    const float* gat_ad = (const float*)d_in[14];
    const float* gat_b  = (const float*)d_in[15];
    const float* ln_s   = (const float*)d_in[16];
    const float* ln_b   = (const float*)d_in[17];
    const int* esrc[8] = {(const int*)d_in[18], (const int*)d_in[20], (const int*)d_in[22],
                          (const int*)d_in[24], (const int*)d_in[26], (const int*)d_in[28],
                          (const int*)d_in[30], (const int*)d_in[32]};
    const int* edst[8] = {(const int*)d_in[19], (const int*)d_in[21], (const int*)d_in[23],
                          (const int*)d_in[25], (const int*)d_in[27], (const int*)d_in[29],
                          (const int*)d_in[31], (const int*)d_in[33]};
    const int* bidx[4] = {(const int*)d_in[34], (const int*)d_in[35],
                          (const int*)d_in[36], (const int*)d_in[37]};
    int E[8];
    {
        const int eidx[8] = {18, 20, 22, 24, 26, 28, 30, 32};
        for (int r = 0; r < 8; ++r) E[r] = in_sizes[eidx[r]];
    }
    const int Kin[4] = {8, 10, 7, 3};
    int N[4];
    for (int t = 0; t < 4; ++t) N[t] = in_sizes[t] / Kin[t];
    const int rel_st[8] = {0, 1, 0, 2, 0, 0, 1, 2};
    const int rel_dt[8] = {1, 0, 2, 0, 3, 0, 3, 3};
    const float cnt_inv[4] = {1.f / 3.f, 1.f, 1.f, 1.f / 3.f};
    int Emax = 0;
    for (int r = 0; r < 8; ++r) Emax = E[r] > Emax ? E[r] : Emax;
    int Nmax = N[0];

    // ---- workspace carve-up (floats) ----
    float* ws = (float*)d_ws;
    size_t off = 0;
    float* x[4];
    for (int t = 0; t < 4; ++t) { x[t] = ws + off; off += (size_t)N[t] * HID; }
    float* acc[4];
    size_t acc_off0 = off;
    for (int t = 0; t < 4; ++t) { acc[t] = ws + off; off += (size_t)N[t] * HID; }
    size_t acc_total = off - acc_off0;
    float* hs  = ws + off; off += (size_t)Nmax * HID;
    float* als = ws + off; off += (size_t)Nmax * NHEAD;
    float* ald = ws + off; off += (size_t)Nmax * NHEAD;
    float* den = ws + off; off += (size_t)Nmax * NHEAD;
    float* ex  = ws + off; off += (size_t)Emax * NHEAD;
    float* vd  = ws + off; off += HID * NHEAD;
    float* bias_sum = ws + off; off += 4 * HID;
    float* cnt = ws + off; off += 4 * NGRAPH;
    (void)ws_size; (void)n_in;

    // ---- 1. input projections ----
    for (int t = 0; t < 4; ++t) {
        int total = N[t] * HID;
        k_proj<<<(total + 255) / 256, 256, 0, stream>>>(x_in[t], Wp[t], bp[t], x[t], N[t], Kin[t]);
    }

    // ---- 2. layers ----
    for (int l = 0; l < 2; ++l) {
        hipMemsetAsync(acc[0], 0, acc_total * sizeof(float), stream);
        for (int r = 0; r < 8; ++r) {
            int st = rel_st[r], dt = rel_dt[r];
            const float* W   = gat_W  + (size_t)(l * 8 + r) * HID * HID;
            const float* a_s = gat_as + (size_t)(l * 8 + r) * HID;
            const float* a_d = gat_ad + (size_t)(l * 8 + r) * HID;
            k_matmul<<<(N[st] + MM_ROWS - 1) / MM_ROWS, 256, 0, stream>>>(x[st], W, hs, N[st]);
            k_als<<<(N[st] * NHEAD + 255) / 256, 256, 0, stream>>>(hs, a_s, als, N[st]);
            k_vd<<<2, 256, 0, stream>>>(W, a_d, vd);
            k_ald<<<(N[dt] * NHEAD + 255) / 256, 256, 0, stream>>>(x[dt], vd, ald, N[dt]);
            hipMemsetAsync(den, 0, (size_t)N[dt] * NHEAD * sizeof(float), stream);
            k_edgeA<<<(E[r] * NHEAD + 255) / 256, 256, 0, stream>>>(esrc[r], edst[r], als, ald, ex, den, E[r]);
            k_edgeB<<<((size_t)E[r] * HID + 255) / 256, 256, 0, stream>>>(esrc[r], edst[r], hs, ex, den, acc[dt], E[r]);
        }
        k_biassum<<<2, 256, 0, stream>>>(gat_b + (size_t)l * 8 * HID, bias_sum);
        for (int t = 0; t < 4; ++t) {
            k_finalize<<<(N[t] + 3) / 4, 256, 0, stream>>>(x[t], acc[t], bias_sum + t * HID,
                                                           cnt_inv[t], ln_s + l * HID, ln_b + l * HID, N[t]);
        }
    }

    // ---- 3. pooling ----
    hipMemsetAsync(d_out, 0, (size_t)out_size * sizeof(float), stream);
    hipMemsetAsync(cnt, 0, 4 * NGRAPH * sizeof(float), stream);
    for (int t = 0; t < 4; ++t) {
        k_pool_accum<<<(N[t] * HID + 255) / 256, 256, 0, stream>>>(x[t], bidx[t], (float*)d_out, N[t], t * HID);
        k_count<<<(N[t] + 255) / 256, 256, 0, stream>>>(bidx[t], cnt, N[t], t * NGRAPH);
    }
    k_pool_div<<<(NGRAPH * 512 + 255) / 256, 256, 0, stream>>>((float*)d_out, cnt);
}

// Round 2
// 5054.026 us; speedup vs baseline: 1.1403x; 1.1403x over previous
//
#include <hip/hip_runtime.h>
#include <cstdint>

#define HID 128
#define NHEAD 4
#define HDIM 32
#define NGRAPH 64
#define MM_ROWS 16

// ---------------- projection: out[N,128] = x[N,K] @ Wp[K,128] + bp ----------------
__global__ void k_proj(const float* __restrict__ x, const float* __restrict__ Wp,
                       const float* __restrict__ bp, float* __restrict__ out,
                       int N, int K) {
    int idx = blockIdx.x * blockDim.x + threadIdx.x;
    if (idx >= N * HID) return;
    int row = idx >> 7, c = idx & 127;
    float acc = bp[c];
    for (int k = 0; k < K; ++k) acc += x[row * K + k] * Wp[k * HID + c];
    out[idx] = acc;
}

// ---------------- hs[N,128] = A[N,128] @ W[128,128] ----------------
__global__ void k_matmul(const float* __restrict__ A, const float* __restrict__ W,
                         float* __restrict__ out, int N) {
    __shared__ float As[MM_ROWS][HID];
    int r0 = blockIdx.x * MM_ROWS;
    int t = threadIdx.x; // 256 threads
    for (int i = t; i < MM_ROWS * HID; i += 256) {
        int r = i >> 7;
        As[r][i & 127] = (r0 + r < N) ? A[(size_t)(r0 + r) * HID + (i & 127)] : 0.f;
    }
    __syncthreads();
    int c = t & 127;
    int rbase = (t >> 7) * (MM_ROWS / 2); // 8 rows per thread
    float acc[MM_ROWS / 2];
#pragma unroll
    for (int r = 0; r < MM_ROWS / 2; ++r) acc[r] = 0.f;
    for (int k = 0; k < HID; ++k) {
        float w = W[k * HID + c];
#pragma unroll
        for (int r = 0; r < MM_ROWS / 2; ++r) acc[r] += As[rbase + r][k] * w;
    }
#pragma unroll
    for (int r = 0; r < MM_ROWS / 2; ++r) {
        int row = r0 + rbase + r;
        if (row < N) out[(size_t)row * HID + c] = acc[r];
    }
}

// ---------------- al_s[i,h] = sum_d hs[i,h*32+d] * a_s[h*32+d] ----------------
__global__ void k_als(const float* __restrict__ hs, const float* __restrict__ a_s,
                      float* __restrict__ als, int N) {
    __shared__ float as_s[HID];
    int t = threadIdx.x;
    if (t < HID) as_s[t] = a_s[t];
    __syncthreads();
    int idx = blockIdx.x * blockDim.x + t;
    if (idx >= N * NHEAD) return;
    int i = idx >> 2, h = idx & 3;
    const float* p = hs + (size_t)i * HID + h * HDIM;
    const float* a = as_s + h * HDIM;
    float s = 0.f;
#pragma unroll
    for (int j = 0; j < HDIM; ++j) s += p[j] * a[j];
    als[idx] = s;
}

// ---------------- vd[k,h] = sum_j W[k, h*32+j] * a_d[h*32+j] ----------------
__global__ void k_vd(const float* __restrict__ W, const float* __restrict__ a_d,
                     float* __restrict__ vd) {
    int idx = blockIdx.x * blockDim.x + threadIdx.x;
    if (idx >= HID * NHEAD) return;
    int k = idx >> 2, h = idx & 3;
    float s = 0.f;
#pragma unroll
    for (int j = 0; j < HDIM; ++j) s += W[k * HID + h * HDIM + j] * a_d[h * HDIM + j];
    vd[idx] = s;
}

// ---------------- al_d[i,h] = sum_k x[i,k] * vd[k,h] ----------------
__global__ void k_ald(const float* __restrict__ x, const float* __restrict__ vd,
                      float* __restrict__ ald, int N) {
    __shared__ float vs[HID * NHEAD];
    int t = threadIdx.x;
    for (int i = t; i < HID * NHEAD; i += blockDim.x) vs[i] = vd[i];
    __syncthreads();
    int idx = blockIdx.x * blockDim.x + t;
    if (idx >= N * NHEAD) return;
    int i = idx >> 2, h = idx & 3;
    const float* row = x + (size_t)i * HID;
    float s = 0.f;
#pragma unroll 8
    for (int k = 0; k < HID; ++k) s += row[k] * vs[k * NHEAD + h];
    ald[idx] = s;
}

// ---------------- edge pass A: den[d,h] += exp(leaky_relu(al_s[src]+al_d[dst])) ----------------
__global__ void k_edgeA(const int* __restrict__ src, const int* __restrict__ dst,
                        const float* __restrict__ als, const float* __restrict__ ald,
                        float* __restrict__ den, int E) {
    int idx = blockIdx.x * blockDim.x + threadIdx.x;
    if (idx >= E * NHEAD) return;
    int e = idx >> 2, h = idx & 3;
    int s = src[e], d = dst[e];
    float a = als[s * NHEAD + h] + ald[d * NHEAD + h];
    a = (a > 0.f) ? a : 0.2f * a;
    atomicAdd(&den[d * NHEAD + h], __expf(a));
}

// ---------------- edge pass B: acc[dst, c] += hs[src, c] * exp(...)/(den+eps) ----------------
__global__ void k_edgeB(const int* __restrict__ src, const int* __restrict__ dst,
                        const float* __restrict__ hs,
                        const float* __restrict__ als, const float* __restrict__ ald,
                        const float* __restrict__ den, float* __restrict__ acc, int E) {
    size_t idx = (size_t)blockIdx.x * blockDim.x + threadIdx.x;
    if (idx >= (size_t)E * HID) return;
    int e = (int)(idx >> 7), c = (int)(idx & 127), h = c >> 5;
    int s = src[e], d = dst[e];
    float a = als[s * NHEAD + h] + ald[d * NHEAD + h];
    a = (a > 0.f) ? a : 0.2f * a;
    float coef = __expf(a) / (den[d * NHEAD + h] + 1e-16f);
    atomicAdd(&acc[(size_t)d * HID + c], hs[(size_t)s * HID + c] * coef);
}

// ---------------- bias_sum[t,c] = sum over relations targeting type t of gat_b[l,r,c] ----------------
__global__ void k_biassum(const float* __restrict__ gat_b_layer, float* __restrict__ bias_sum) {
    int idx = blockIdx.x * blockDim.x + threadIdx.x;
    if (idx >= 4 * HID) return;
    int t = idx >> 7, c = idx & 127;
    const int rels[4][3] = {{1, 3, 5}, {0, -1, -1}, {2, -1, -1}, {4, 6, 7}};
    float s = 0.f;
#pragma unroll
    for (int j = 0; j < 3; ++j) {
        int r = rels[t][j];
        if (r >= 0) s += gat_b_layer[r * HID + c];
    }
    bias_sum[idx] = s;
}

// ---------------- finalize: x = LN(relu((acc+bias_sum)*cnt_inv) + x) ----------------
__global__ void k_finalize(float* __restrict__ x, const float* __restrict__ acc,
                           const float* __restrict__ bias_sum, float cnt_inv,
                           const float* __restrict__ ln_s, const float* __restrict__ ln_b,
                           int N) {
    int gwave = (blockIdx.x * blockDim.x + threadIdx.x) >> 6;
    int lane = threadIdx.x & 63;
    if (gwave >= N) return;
    float y[2];
    float s = 0.f, ss = 0.f;
#pragma unroll
    for (int i = 0; i < 2; ++i) {
        int c = i * 64 + lane; // coalesced
        float v = (acc[(size_t)gwave * HID + c] + bias_sum[c]) * cnt_inv;
        v = v > 0.f ? v : 0.f;
        v += x[(size_t)gwave * HID + c];
        y[i] = v;
        s += v;
        ss += v * v;
    }
#pragma unroll
    for (int off = 32; off; off >>= 1) {
        s += __shfl_down(s, off);
        ss += __shfl_down(ss, off);
    }
    s = __shfl(s, 0);
    ss = __shfl(ss, 0);
    float mu = s * (1.f / HID);
    float var = ss * (1.f / HID) - mu * mu;
    float rstd = rsqrtf(var + 1e-5f);
#pragma unroll
    for (int i = 0; i < 2; ++i) {
        int c = i * 64 + lane;
        x[(size_t)gwave * HID + c] = (y[i] - mu) * rstd * ln_s[c] + ln_b[c];
    }
}

// ---------------- pooling: sorted batch idx -> binary-searched segment mean, no atomics ----------------
__global__ void k_pool(const float* __restrict__ x0, const float* __restrict__ x1,
                       const float* __restrict__ x2, const float* __restrict__ x3,
                       const int* __restrict__ b0, const int* __restrict__ b1,
                       const int* __restrict__ b2, const int* __restrict__ b3,
                       int N0, int N1, int N2, int N3, float* __restrict__ out) {
    int t = blockIdx.y, g = blockIdx.x;
    const float* x = (t == 0) ? x0 : (t == 1) ? x1 : (t == 2) ? x2 : x3;
    const int* b = (t == 0) ? b0 : (t == 1) ? b1 : (t == 2) ? b2 : b3;
    int N = (t == 0) ? N0 : (t == 1) ? N1 : (t == 2) ? N2 : N3;
    // binary search [start, end): b is sorted ascending, values in [0, NGRAPH)
    int lo = 0, hi = N;
    while (lo < hi) { int m = (lo + hi) >> 1; if (b[m] < g) lo = m + 1; else hi = m; }
    int start = lo;
    hi = N;
    while (lo < hi) { int m = (lo + hi) >> 1; if (b[m] < g + 1) lo = m + 1; else hi = m; }
    int end = lo;
    int c = threadIdx.x; // 128 threads, coalesced across columns
    float s = 0.f;
    for (int i = start; i < end; ++i) s += x[(size_t)i * HID + c];
    float cntf = (float)(end - start);
    out[g * 512 + t * HID + c] = s / fmaxf(cntf, 1.0f);
}

extern "C" void kernel_launch(void* const* d_in, const int* in_sizes, int n_in,
                              void* d_out, int out_size, void* d_ws, size_t ws_size,
                              hipStream_t stream) {
    const float* x_in[4] = {(const float*)d_in[0], (const float*)d_in[1],
                            (const float*)d_in[2], (const float*)d_in[3]};
    const float* Wp[4] = {(const float*)d_in[4], (const float*)d_in[6],
                          (const float*)d_in[8], (const float*)d_in[10]};
    const float* bp[4] = {(const float*)d_in[5], (const float*)d_in[7],
                          (const float*)d_in[9], (const float*)d_in[11]};
    const float* gat_W  = (const float*)d_in[12];
    const float* gat_as = (const float*)d_in[13];
    const float* gat_ad = (const float*)d_in[14];
    const float* gat_b  = (const float*)d_in[15];
    const float* ln_s   = (const float*)d_in[16];
    const float* ln_b   = (const float*)d_in[17];
    const int* esrc[8] = {(const int*)d_in[18], (const int*)d_in[20], (const int*)d_in[22],
                          (const int*)d_in[24], (const int*)d_in[26], (const int*)d_in[28],
                          (const int*)d_in[30], (const int*)d_in[32]};
    const int* edst[8] = {(const int*)d_in[19], (const int*)d_in[21], (const int*)d_in[23],
                          (const int*)d_in[25], (const int*)d_in[27], (const int*)d_in[29],
                          (const int*)d_in[31], (const int*)d_in[33]};
    const int* bidx[4] = {(const int*)d_in[34], (const int*)d_in[35],
                          (const int*)d_in[36], (const int*)d_in[37]};
    int E[8];
    {
        const int eidx[8] = {18, 20, 22, 24, 26, 28, 30, 32};
        for (int r = 0; r < 8; ++r) E[r] = in_sizes[eidx[r]];
    }
    const int Kin[4] = {8, 10, 7, 3};
    int N[4];
    for (int t = 0; t < 4; ++t) N[t] = in_sizes[t] / Kin[t];
    const int rel_st[8] = {0, 1, 0, 2, 0, 0, 1, 2};
    const int rel_dt[8] = {1, 0, 2, 0, 3, 0, 3, 3};
    const float cnt_inv[4] = {1.f / 3.f, 1.f, 1.f, 1.f / 3.f};
    int Nmax = N[0];

    // ---- workspace carve-up (floats) ----
    float* ws = (float*)d_ws;
    size_t off = 0;
    float* x[4];
    for (int t = 0; t < 4; ++t) { x[t] = ws + off; off += (size_t)N[t] * HID; }
    float* acc[4];
    size_t acc_off0 = off;
    for (int t = 0; t < 4; ++t) { acc[t] = ws + off; off += (size_t)N[t] * HID; }
    size_t acc_total = off - acc_off0;
    float* hs  = ws + off; off += (size_t)Nmax * HID;
    float* als = ws + off; off += (size_t)Nmax * NHEAD;
    float* ald = ws + off; off += (size_t)Nmax * NHEAD;
    float* den = ws + off; off += (size_t)Nmax * NHEAD;
    float* vd  = ws + off; off += HID * NHEAD;
    float* bias_sum = ws + off; off += 4 * HID;
    (void)ws_size; (void)n_in;

    // ---- 1. input projections ----
    for (int t = 0; t < 4; ++t) {
        int total = N[t] * HID;
        k_proj<<<(total + 255) / 256, 256, 0, stream>>>(x_in[t], Wp[t], bp[t], x[t], N[t], Kin[t]);
    }

    // ---- 2. layers ----
    for (int l = 0; l < 2; ++l) {
        hipMemsetAsync(acc[0], 0, acc_total * sizeof(float), stream);
        for (int r = 0; r < 8; ++r) {
            int st = rel_st[r], dt = rel_dt[r];
            const float* W   = gat_W  + (size_t)(l * 8 + r) * HID * HID;
            const float* a_s = gat_as + (size_t)(l * 8 + r) * HID;
            const float* a_d = gat_ad + (size_t)(l * 8 + r) * HID;
            k_matmul<<<(N[st] + MM_ROWS - 1) / MM_ROWS, 256, 0, stream>>>(x[st], W, hs, N[st]);
            k_als<<<(N[st] * NHEAD + 255) / 256, 256, 0, stream>>>(hs, a_s, als, N[st]);
            k_vd<<<2, 256, 0, stream>>>(W, a_d, vd);
            k_ald<<<(N[dt] * NHEAD + 255) / 256, 256, 0, stream>>>(x[dt], vd, ald, N[dt]);
            hipMemsetAsync(den, 0, (size_t)N[dt] * NHEAD * sizeof(float), stream);
            k_edgeA<<<(E[r] * NHEAD + 255) / 256, 256, 0, stream>>>(esrc[r], edst[r], als, ald, den, E[r]);
            k_edgeB<<<(int)(((size_t)E[r] * HID + 255) / 256), 256, 0, stream>>>(esrc[r], edst[r], hs, als, ald, den, acc[dt], E[r]);
        }
        k_biassum<<<2, 256, 0, stream>>>(gat_b + (size_t)l * 8 * HID, bias_sum);
        for (int t = 0; t < 4; ++t) {
            k_finalize<<<(N[t] + 3) / 4, 256, 0, stream>>>(x[t], acc[t], bias_sum + t * HID,
                                                           cnt_inv[t], ln_s + l * HID, ln_b + l * HID, N[t]);
        }
    }

    // ---- 3. pooling (no atomics; sorted batch indices) ----
    {
        dim3 grid(NGRAPH, 4);
        k_pool<<<grid, HID, 0, stream>>>(x[0], x[1], x[2], x[3],
                                         bidx[0], bidx[1], bidx[2], bidx[3],
                                         N[0], N[1], N[2], N[3], (float*)d_out);
    }
}

// Round 3
// 3328.012 us; speedup vs baseline: 1.7316x; 1.5186x over previous
//
#include <hip/hip_runtime.h>
#include <hip/hip_bf16.h>
#include <cstdint>

#define HID 128
#define NHEAD 4
#define NGRAPH 64
#define MM_ROWS 16
#define CAP 512

// ---------------- projection: out[N,128] = x[N,K] @ Wp[K,128] + bp ----------------
__global__ void k_proj(const float* __restrict__ x, const float* __restrict__ Wp,
                       const float* __restrict__ bp, float* __restrict__ out,
                       int N, int K) {
    int idx = blockIdx.x * blockDim.x + threadIdx.x;
    if (idx >= N * HID) return;
    int row = idx >> 7, c = idx & 127;
    float acc = bp[c];
    for (int k = 0; k < K; ++k) acc += x[row * K + k] * Wp[k * HID + c];
    out[idx] = acc;
}

// ---------------- hs[N,128] = A[N,128] @ W[128,128], bf16 out ----------------
__global__ void k_matmul(const float* __restrict__ A, const float* __restrict__ W,
                         __hip_bfloat16* __restrict__ out, int N) {
    __shared__ float As[MM_ROWS][HID + 4]; // +4: breaks 8-way bank conflict, keeps 16B align
    int r0 = blockIdx.x * MM_ROWS;
    int t = threadIdx.x; // 256
    for (int i = t; i < MM_ROWS * HID; i += 256) {
        int r = i >> 7, c = i & 127;
        As[r][c] = (r0 + r < N) ? A[(size_t)(r0 + r) * HID + c] : 0.f;
    }
    __syncthreads();
    int c = t & 127;
    int rbase = (t >> 7) * 8;
    float acc[8];
#pragma unroll
    for (int r = 0; r < 8; ++r) acc[r] = 0.f;
    for (int k = 0; k < HID; k += 4) {
        float w0 = W[k * HID + c], w1 = W[(k + 1) * HID + c];
        float w2 = W[(k + 2) * HID + c], w3 = W[(k + 3) * HID + c];
#pragma unroll
        for (int r = 0; r < 8; ++r) {
            const float4 a = *(const float4*)&As[rbase + r][k];
            acc[r] += a.x * w0 + a.y * w1 + a.z * w2 + a.w * w3;
        }
    }
#pragma unroll
    for (int r = 0; r < 8; ++r) {
        int row = r0 + rbase + r;
        if (row < N) out[(size_t)row * HID + c] = __float2bfloat16(acc[r]);
    }
}

// ---------------- al_s[i,h] = sum_d hs[i,h*32+d] * a_s[h*32+d] ----------------
__global__ void k_als(const __hip_bfloat16* __restrict__ hs, const float* __restrict__ a_s,
                      float* __restrict__ als, int N) {
    __shared__ float as_s[HID];
    int t = threadIdx.x;
    if (t < HID) as_s[t] = a_s[t];
    __syncthreads();
    int idx = blockIdx.x * blockDim.x + t;
    if (idx >= N * NHEAD) return;
    int i = idx >> 2, h = idx & 3;
    const __hip_bfloat16* p = hs + (size_t)i * HID + h * 32;
    const float* a = as_s + h * 32;
    float s = 0.f;
#pragma unroll
    for (int j = 0; j < 32; ++j) s += __bfloat162float(p[j]) * a[j];
    als[idx] = s;
}

// ---------------- vd[k,h] = sum_j W[k, h*32+j] * a_d[h*32+j] ----------------
__global__ void k_vd(const float* __restrict__ W, const float* __restrict__ a_d,
                     float* __restrict__ vd) {
    int idx = blockIdx.x * blockDim.x + threadIdx.x;
    if (idx >= HID * NHEAD) return;
    int k = idx >> 2, h = idx & 3;
    float s = 0.f;
#pragma unroll
    for (int j = 0; j < 32; ++j) s += W[k * HID + h * 32 + j] * a_d[h * 32 + j];
    vd[idx] = s;
}

// ---------------- al_d[i,h] = sum_k x[i,k] * vd[k,h] ----------------
__global__ void k_ald(const float* __restrict__ x, const float* __restrict__ vd,
                      float* __restrict__ ald, int N) {
    __shared__ float vs[HID * NHEAD];
    int t = threadIdx.x;
    for (int i = t; i < HID * NHEAD; i += blockDim.x) vs[i] = vd[i];
    __syncthreads();
    int idx = blockIdx.x * blockDim.x + t;
    if (idx >= N * NHEAD) return;
    int i = idx >> 2, h = idx & 3;
    const float* row = x + (size_t)i * HID;
    float s = 0.f;
#pragma unroll 8
    for (int k = 0; k < HID; ++k) s += row[k] * vs[k * NHEAD + h];
    ald[idx] = s;
}

// ---------------- CSR build ----------------
__global__ void k_hist(const int* __restrict__ dst, int* __restrict__ deg, int E) {
    int e = blockIdx.x * blockDim.x + threadIdx.x;
    if (e < E) atomicAdd(&deg[dst[e]], 1);
}
__global__ void k_scan_part(const int* __restrict__ deg, int* __restrict__ part, int N) {
    __shared__ int sh[256];
    int t = threadIdx.x, i = blockIdx.x * 256 + t;
    sh[t] = (i < N) ? deg[i] : 0;
    __syncthreads();
    for (int o = 128; o; o >>= 1) {
        if (t < o) sh[t] += sh[t + o];
        __syncthreads();
    }
    if (t == 0) part[blockIdx.x] = sh[0];
}
__global__ void k_scan_top(int* __restrict__ part, int n) {
    if (threadIdx.x == 0) {
        int run = 0;
        for (int i = 0; i < n; ++i) { int v = part[i]; part[i] = run; run += v; }
    }
}
__global__ void k_scan_down(const int* __restrict__ deg, const int* __restrict__ part,
                            int* __restrict__ offs, int* __restrict__ cur, int N) {
    __shared__ int sh[256];
    int t = threadIdx.x, i = blockIdx.x * 256 + t;
    int v = (i < N) ? deg[i] : 0;
    sh[t] = v;
    __syncthreads();
    for (int o = 1; o < 256; o <<= 1) {
        int tmp = (t >= o) ? sh[t - o] : 0;
        __syncthreads();
        sh[t] += tmp;
        __syncthreads();
    }
    if (i < N) {
        int excl = sh[t] - v + part[blockIdx.x];
        offs[i] = excl;
        cur[i] = excl;
    }
}
__global__ void k_scatter(const int* __restrict__ src, const int* __restrict__ dst,
                          int* __restrict__ cur, int* __restrict__ adj, int E) {
    int e = blockIdx.x * blockDim.x + threadIdx.x;
    if (e >= E) return;
    int slot = atomicAdd(&cur[dst[e]], 1);
    adj[slot] = src[e];
}

// ---------------- fused per-dst GAT + mean + relu + residual + LN ----------------
struct RelArg {
    const __hip_bfloat16* hs;
    const float* als;
    const float* ald;
    const int* adj;
    const int* off;
    const int* deg;
    const float* bias;
};

__global__ void k_dst(RelArg r0, RelArg r1, RelArg r2, int nrel, float inv_nrel,
                      float* __restrict__ x, const float* __restrict__ ln_s,
                      const float* __restrict__ ln_b, int N) {
    __shared__ float wcache[CAP][4];
    __shared__ int scache[CAP];
    __shared__ float red[128];
    __shared__ float den_sh[4];
    __shared__ float rs[2], rss[2];
    int d = blockIdx.x;
    int t = threadIdx.x; // 128
    int c = t;
    int h1 = t & 3;   // phase1 head
    int h2 = t >> 5;  // phase2 head (c/32)
    float xv = x[(size_t)d * HID + c];
    float relsum = 0.f;
    for (int rr = 0; rr < nrel; ++rr) {
        const RelArg& R = (rr == 0) ? r0 : (rr == 1) ? r1 : r2;
        int base = R.off[d];
        int dg = R.deg[d];
        __syncthreads(); // protect caches from previous relation's readers
        // phase 1: per-head denominator + weight cache
        float ald1 = R.ald[d * NHEAD + h1];
        float denp = 0.f;
        for (int k = (t >> 2); k < dg; k += 32) {
            int s = R.adj[base + k];
            float a = R.als[s * NHEAD + h1] + ald1;
            a = (a > 0.f) ? a : 0.2f * a;
            float w = __expf(a);
            if (k < CAP) {
                wcache[k][h1] = w;
                if (h1 == 0) scache[k] = s;
            }
            denp += w;
        }
        red[t] = denp;
        __syncthreads();
        if (t < 4) {
            float s = 0.f;
            for (int j = 0; j < 32; ++j) s += red[t + 4 * j];
            den_sh[t] = s;
        }
        __syncthreads();
        // phase 2: weighted gather of hs rows
        float ald2 = R.ald[d * NHEAD + h2];
        float acc = 0.f;
        for (int k = 0; k < dg; ++k) {
            int s; float w;
            if (k < CAP) {
                s = scache[k];
                w = wcache[k][h2];
            } else {
                s = R.adj[base + k];
                float a = R.als[s * NHEAD + h2] + ald2;
                a = (a > 0.f) ? a : 0.2f * a;
                w = __expf(a);
            }
            acc += w * __bfloat162float(R.hs[(size_t)s * HID + c]);
        }
        relsum += acc / (den_sh[h2] + 1e-16f) + R.bias[c];
    }
    float v = relsum * inv_nrel;
    v = (v > 0.f) ? v : 0.f;
    v += xv;
    // block LayerNorm over 128 channels
    float s = v, ss = v * v;
#pragma unroll
    for (int o = 32; o; o >>= 1) { s += __shfl_down(s, o); ss += __shfl_down(ss, o); }
    int wid = t >> 6, lane = t & 63;
    if (lane == 0) { rs[wid] = s; rss[wid] = ss; }
    __syncthreads();
    float S = rs[0] + rs[1], SS = rss[0] + rss[1];
    float mu = S * (1.f / HID);
    float var = SS * (1.f / HID) - mu * mu;
    float rstd = rsqrtf(var + 1e-5f);
    x[(size_t)d * HID + c] = (v - mu) * rstd * ln_s[c] + ln_b[c];
}

// ---------------- pooling: chunked segment sums (sorted batch idx) ----------------
__global__ void k_pool_part(const float* __restrict__ x, const int* __restrict__ b,
                            int N, int toff, float* __restrict__ out) {
    int r0 = blockIdx.x * 512;
    if (r0 >= N) return;
    int rend = min(r0 + 512, N);
    int c = threadIdx.x; // 128
    int cur = b[r0];
    float acc = 0.f;
    for (int i = r0; i < rend; ++i) {
        int g = b[i];
        if (g != cur) {
            atomicAdd(&out[cur * 512 + toff + c], acc);
            acc = 0.f;
            cur = g;
        }
        acc += x[(size_t)i * HID + c];
    }
    atomicAdd(&out[cur * 512 + toff + c], acc);
}
__global__ void k_cnt(const int* __restrict__ b0, const int* __restrict__ b1,
                      const int* __restrict__ b2, const int* __restrict__ b3,
                      int N0, int N1, int N2, int N3, float* __restrict__ cnt) {
    int i = blockIdx.x * blockDim.x + threadIdx.x;
    if (i >= 256) return;
    int t = i >> 6, g = i & 63;
    const int* b = (t == 0) ? b0 : (t == 1) ? b1 : (t == 2) ? b2 : b3;
    int N = (t == 0) ? N0 : (t == 1) ? N1 : (t == 2) ? N2 : N3;
    int lo = 0, hi = N;
    while (lo < hi) { int m = (lo + hi) >> 1; if (b[m] < g) lo = m + 1; else hi = m; }
    int s = lo;
    hi = N;
    while (lo < hi) { int m = (lo + hi) >> 1; if (b[m] < g + 1) lo = m + 1; else hi = m; }
    cnt[i] = (float)(lo - s);
}
__global__ void k_div(float* __restrict__ out, const float* __restrict__ cnt) {
    int idx = blockIdx.x * blockDim.x + threadIdx.x;
    if (idx >= NGRAPH * 512) return;
    int g = idx >> 9, c = idx & 511, t = c >> 7;
    out[idx] = out[idx] / fmaxf(cnt[t * NGRAPH + g], 1.0f);
}

extern "C" void kernel_launch(void* const* d_in, const int* in_sizes, int n_in,
                              void* d_out, int out_size, void* d_ws, size_t ws_size,
                              hipStream_t stream) {
    const float* x_in[4] = {(const float*)d_in[0], (const float*)d_in[1],
                            (const float*)d_in[2], (const float*)d_in[3]};
    const float* Wp[4] = {(const float*)d_in[4], (const float*)d_in[6],
                          (const float*)d_in[8], (const float*)d_in[10]};
    const float* bp[4] = {(const float*)d_in[5], (const float*)d_in[7],
                          (const float*)d_in[9], (const float*)d_in[11]};
    const float* gat_W  = (const float*)d_in[12];
    const float* gat_as = (const float*)d_in[13];
    const float* gat_ad = (const float*)d_in[14];
    const float* gat_b  = (const float*)d_in[15];
    const float* ln_s   = (const float*)d_in[16];
    const float* ln_b   = (const float*)d_in[17];
    const int* esrc[8] = {(const int*)d_in[18], (const int*)d_in[20], (const int*)d_in[22],
                          (const int*)d_in[24], (const int*)d_in[26], (const int*)d_in[28],
                          (const int*)d_in[30], (const int*)d_in[32]};
    const int* edst[8] = {(const int*)d_in[19], (const int*)d_in[21], (const int*)d_in[23],
                          (const int*)d_in[25], (const int*)d_in[27], (const int*)d_in[29],
                          (const int*)d_in[31], (const int*)d_in[33]};
    const int* bidx[4] = {(const int*)d_in[34], (const int*)d_in[35],
                          (const int*)d_in[36], (const int*)d_in[37]};
    int E[8];
    {
        const int eidx[8] = {18, 20, 22, 24, 26, 28, 30, 32};
        for (int r = 0; r < 8; ++r) E[r] = in_sizes[eidx[r]];
    }
    const int Kin[4] = {8, 10, 7, 3};
    int N[4];
    for (int t = 0; t < 4; ++t) N[t] = in_sizes[t] / Kin[t];
    const int rel_st[8] = {0, 1, 0, 2, 0, 0, 1, 2};
    const int rel_dt[8] = {1, 0, 2, 0, 3, 0, 3, 3};
    (void)ws_size; (void)n_in;

    // ---- workspace carve-up (byte offsets, 16B aligned) ----
    char* base = (char*)d_ws;
    size_t cur = 0;
    auto alloc = [&](size_t bytes) -> void* {
        void* p = base + cur;
        cur += (bytes + 15) & ~(size_t)15;
        return p;
    };
    float* x[4];
    for (int t = 0; t < 4; ++t) x[t] = (float*)alloc((size_t)N[t] * HID * 4);
    __hip_bfloat16* hs[8];
    float *als_[8], *ald_[8];
    int *deg[8], *offs[8], *curs[8], *adj[8];
    for (int r = 0; r < 8; ++r) {
        int Ns = N[rel_st[r]], Nd = N[rel_dt[r]];
        hs[r]   = (__hip_bfloat16*)alloc((size_t)Ns * HID * 2);
        als_[r] = (float*)alloc((size_t)Ns * NHEAD * 4);
        ald_[r] = (float*)alloc((size_t)Nd * NHEAD * 4);
        deg[r]  = (int*)alloc((size_t)Nd * 4);
        offs[r] = (int*)alloc((size_t)Nd * 4);
        curs[r] = (int*)alloc((size_t)Nd * 4);
        adj[r]  = (int*)alloc((size_t)E[r] * 4);
    }
    float* vd   = (float*)alloc(HID * NHEAD * 4);
    int* part   = (int*)alloc(512 * 4);
    float* cntf = (float*)alloc(256 * 4);

    // ---- 0. CSR build (per relation) ----
    for (int r = 0; r < 8; ++r) {
        int Nd = N[rel_dt[r]];
        int nparts = (Nd + 255) / 256;
        hipMemsetAsync(deg[r], 0, (size_t)Nd * 4, stream);
        k_hist<<<(E[r] + 255) / 256, 256, 0, stream>>>(edst[r], deg[r], E[r]);
        k_scan_part<<<nparts, 256, 0, stream>>>(deg[r], part, Nd);
        k_scan_top<<<1, 64, 0, stream>>>(part, nparts);
        k_scan_down<<<nparts, 256, 0, stream>>>(deg[r], part, offs[r], curs[r], Nd);
        k_scatter<<<(E[r] + 255) / 256, 256, 0, stream>>>(esrc[r], edst[r], curs[r], adj[r], E[r]);
    }

    // ---- 1. input projections ----
    for (int t = 0; t < 4; ++t)
        k_proj<<<(N[t] * HID + 255) / 256, 256, 0, stream>>>(x_in[t], Wp[t], bp[t], x[t], N[t], Kin[t]);

    // ---- 2. layers ----
    for (int l = 0; l < 2; ++l) {
        for (int r = 0; r < 8; ++r) {
            int st = rel_st[r], dt = rel_dt[r];
            const float* W   = gat_W  + (size_t)(l * 8 + r) * HID * HID;
            const float* a_s = gat_as + (size_t)(l * 8 + r) * HID;
            const float* a_d = gat_ad + (size_t)(l * 8 + r) * HID;
            k_matmul<<<(N[st] + MM_ROWS - 1) / MM_ROWS, 256, 0, stream>>>(x[st], W, hs[r], N[st]);
            k_als<<<(N[st] * NHEAD + 255) / 256, 256, 0, stream>>>(hs[r], a_s, als_[r], N[st]);
            k_vd<<<2, 256, 0, stream>>>(W, a_d, vd);
            k_ald<<<(N[dt] * NHEAD + 255) / 256, 256, 0, stream>>>(x[dt], vd, ald_[r], N[dt]);
        }
        auto mk = [&](int r) {
            RelArg a;
            a.hs = hs[r]; a.als = als_[r]; a.ald = ald_[r];
            a.adj = adj[r]; a.off = offs[r]; a.deg = deg[r];
            a.bias = gat_b + (size_t)(l * 8 + r) * HID;
            return a;
        };
        const float* ls = ln_s + l * HID;
        const float* lb = ln_b + l * HID;
        // dst type b: rels 1,3,5 ; s: 0 ; c: 2 ; f: 4,6,7
        k_dst<<<N[0], 128, 0, stream>>>(mk(1), mk(3), mk(5), 3, 1.f / 3.f, x[0], ls, lb, N[0]);
        k_dst<<<N[1], 128, 0, stream>>>(mk(0), mk(0), mk(0), 1, 1.f, x[1], ls, lb, N[1]);
        k_dst<<<N[2], 128, 0, stream>>>(mk(2), mk(2), mk(2), 1, 1.f, x[2], ls, lb, N[2]);
        k_dst<<<N[3], 128, 0, stream>>>(mk(4), mk(6), mk(7), 3, 1.f / 3.f, x[3], ls, lb, N[3]);
    }

    // ---- 3. pooling ----
    hipMemsetAsync(d_out, 0, (size_t)out_size * 4, stream);
    k_cnt<<<1, 256, 0, stream>>>(bidx[0], bidx[1], bidx[2], bidx[3],
                                 N[0], N[1], N[2], N[3], cntf);
    for (int t = 0; t < 4; ++t)
        k_pool_part<<<(N[t] + 511) / 512, 128, 0, stream>>>(x[t], bidx[t], N[t], t * HID, (float*)d_out);
    k_div<<<(NGRAPH * 512 + 255) / 256, 256, 0, stream>>>((float*)d_out, cntf);
}

// Round 4
// 3158.505 us; speedup vs baseline: 1.8246x; 1.0537x over previous
//
#include <hip/hip_runtime.h>
#include <hip/hip_bf16.h>
#include <cstdint>

#define HID 128
#define NHEAD 4
#define NGRAPH 64
#define CAP 512

typedef __attribute__((ext_vector_type(8))) short bf16x8;
typedef __attribute__((ext_vector_type(4))) float f32x4;

// ---------------- projection: out[N,128] = x[N,K] @ Wp[K,128] + bp (fp32 + bf16 copies) ----------------
__global__ void k_proj(const float* __restrict__ x, const float* __restrict__ Wp,
                       const float* __restrict__ bp, float* __restrict__ out,
                       __hip_bfloat16* __restrict__ outb, int N, int K) {
    int idx = blockIdx.x * blockDim.x + threadIdx.x;
    if (idx >= N * HID) return;
    int row = idx >> 7, c = idx & 127;
    float acc = bp[c];
    for (int k = 0; k < K; ++k) acc += x[row * K + k] * Wp[k * HID + c];
    out[idx] = acc;
    outb[idx] = __float2bfloat16(acc);
}

// ---------------- cast+swizzle W into per-(layer,group) concatenated bf16, MFMA-B-friendly ----------------
// dest element (k,n) at ((k>>3)*Ncols + n)*8 + (k&7)
__global__ void k_castW(const float* __restrict__ gat_W, __hip_bfloat16* __restrict__ Wsw) {
    int idx = blockIdx.x * blockDim.x + threadIdx.x; // 2*128*1024
    if (idx >= 262144) return;
    int l = idx >> 17;
    int rem = idx & 131071;
    int k = rem >> 10;
    int gc = rem & 1023;
    int rel, n, gobase, Ncols;
    if (gc < 512) {
        int i = gc >> 7;
        rel = (i == 0) ? 0 : (i == 1) ? 2 : (i == 2) ? 4 : 5;
        n = gc & 127 | ((gc >> 7) << 7); // n within group = gc
        n = gc; gobase = 0; Ncols = 512;
    } else if (gc < 768) {
        int c2 = gc - 512;
        rel = (c2 >> 7) ? 6 : 1;
        n = c2; gobase = 65536; Ncols = 256;
    } else {
        int c2 = gc - 768;
        rel = (c2 >> 7) ? 7 : 3;
        n = c2; gobase = 98304; Ncols = 256;
    }
    int nl = n & 127;
    float v = gat_W[(((size_t)l * 8 + rel) * 128 + k) * 128 + nl];
    size_t dst = (size_t)l * 131072 + gobase + ((size_t)(k >> 3) * Ncols + n) * 8 + (k & 7);
    Wsw[dst] = __float2bfloat16(v);
}

// ---------------- vecall[l][r*2+side][k][h] = sum_j W[l,r,k,h*32+j] * a[l,r,h*32+j] ----------------
__global__ void k_mkvec(const float* __restrict__ gat_W, const float* __restrict__ gat_as,
                        const float* __restrict__ gat_ad, float* __restrict__ vecall) {
    int idx = blockIdx.x * blockDim.x + threadIdx.x; // 2*16*128*4
    if (idx >= 16384) return;
    int h = idx & 3, k = (idx >> 2) & 127, p = (idx >> 9) & 15, l = idx >> 13;
    int r = p >> 1, side = p & 1;
    const float* W = gat_W + (((size_t)l * 8 + r) * 128 + k) * 128;
    const float* a = (side ? gat_ad : gat_as) + ((size_t)l * 8 + r) * 128;
    float s = 0.f;
#pragma unroll
    for (int j = 0; j < 32; ++j) s += W[h * 32 + j] * a[h * 32 + j];
    vecall[((size_t)l * 16 + p) * 512 + k * 4 + h] = s;
}

// ---------------- MFMA GEMM: out[M,Ncols](bf16) = A[M,128](bf16) @ Bsw ----------------
__global__ __launch_bounds__(256) void k_gemm(const __hip_bfloat16* __restrict__ Abf,
                                              const __hip_bfloat16* __restrict__ Bsw,
                                              __hip_bfloat16* __restrict__ out,
                                              int M, int Ncols) {
    __shared__ __hip_bfloat16 Alds[64][136];
    int m0 = blockIdx.x * 64;
    int n0 = blockIdx.y * 128;
    int t = threadIdx.x;
    // stage A tile (64x128 bf16, uint4 chunks)
    for (int i = t; i < 1024; i += 256) {
        int row = i >> 4, ch = i & 15;
        uint4 v = make_uint4(0u, 0u, 0u, 0u);
        if (m0 + row < M) v = *(const uint4*)(Abf + ((size_t)(m0 + row) * 128 + ch * 8));
        *(uint4*)&Alds[row][ch * 8] = v;
    }
    __syncthreads();
    int w = t >> 6, l = t & 63;
    int lane16 = l & 15, q = l >> 4;
    f32x4 acc[8];
#pragma unroll
    for (int nn = 0; nn < 8; ++nn) acc[nn] = (f32x4){0.f, 0.f, 0.f, 0.f};
    const __hip_bfloat16* arow = &Alds[w * 16 + lane16][q * 8];
#pragma unroll
    for (int kk = 0; kk < 4; ++kk) {
        bf16x8 a = *(const bf16x8*)(arow + kk * 32);
#pragma unroll
        for (int nn = 0; nn < 8; ++nn) {
            size_t boff = ((size_t)(kk * 4 + q) * Ncols + (n0 + nn * 16 + lane16)) * 8;
            bf16x8 b = *(const bf16x8*)(Bsw + boff);
            acc[nn] = __builtin_amdgcn_mfma_f32_16x16x32_bf16(a, b, acc[nn], 0, 0, 0);
        }
    }
    int orow = m0 + w * 16 + q * 4;
#pragma unroll
    for (int nn = 0; nn < 8; ++nn) {
        int col = n0 + nn * 16 + lane16;
#pragma unroll
        for (int r = 0; r < 4; ++r) {
            int row = orow + r;
            if (row < M) out[(size_t)row * Ncols + col] = __float2bfloat16(acc[nn][r]);
        }
    }
}

// ---------------- fused logits: for up to 8 (vec,out) pairs, out[i,h] = x[i,:]·vec[:,h] ----------------
struct LogitPack {
    const float* vec[8];
    float* out[8];
};

__global__ __launch_bounds__(256) void k_logits(const float* __restrict__ x, int N, int nvec,
                                                LogitPack P) {
    __shared__ float vs[8][128][4];
    __shared__ float xs[64][129];
    int t = threadIdx.x;
    int nb = blockIdx.x * 64;
    for (int i = t; i < nvec * 512; i += 256) {
        int v = i >> 9, j = i & 511;
        vs[v][j >> 2][j & 3] = P.vec[v][j];
    }
    for (int i = t; i < 64 * 128; i += 256) {
        int r = i >> 7, k = i & 127;
        xs[r][k] = (nb + r < N) ? x[(size_t)(nb + r) * 128 + k] : 0.f;
    }
    __syncthreads();
    int nl = t >> 2, h = t & 3;
    int node = nb + nl;
    float acc[8];
#pragma unroll
    for (int v = 0; v < 8; ++v) acc[v] = 0.f;
    for (int k = 0; k < 128; ++k) {
        float xv = xs[nl][k];
        for (int v = 0; v < nvec; ++v) acc[v] += xv * vs[v][k][h];
    }
    if (node < N)
        for (int v = 0; v < nvec; ++v) P.out[v][node * 4 + h] = acc[v];
}

// ---------------- CSR build ----------------
__global__ void k_hist(const int* __restrict__ dst, int* __restrict__ deg, int E) {
    int e = blockIdx.x * blockDim.x + threadIdx.x;
    if (e < E) atomicAdd(&deg[dst[e]], 1);
}
__global__ void k_scan_part(const int* __restrict__ deg, int* __restrict__ part, int N) {
    __shared__ int sh[256];
    int t = threadIdx.x, i = blockIdx.x * 256 + t;
    sh[t] = (i < N) ? deg[i] : 0;
    __syncthreads();
    for (int o = 128; o; o >>= 1) {
        if (t < o) sh[t] += sh[t + o];
        __syncthreads();
    }
    if (t == 0) part[blockIdx.x] = sh[0];
}
// block-parallel exclusive scan over up to 512 partials (replaces serial loop)
__global__ void k_scan_top(int* __restrict__ part, int n) {
    __shared__ int sh[512];
    int t = threadIdx.x;
    int v = (t < n) ? part[t] : 0;
    sh[t] = v;
    __syncthreads();
    for (int o = 1; o < 512; o <<= 1) {
        int tmp = (t >= o) ? sh[t - o] : 0;
        __syncthreads();
        sh[t] += tmp;
        __syncthreads();
    }
    if (t < n) part[t] = sh[t] - v;
}
__global__ void k_scan_down(const int* __restrict__ deg, const int* __restrict__ part,
                            int* __restrict__ offs, int* __restrict__ cur, int N) {
    __shared__ int sh[256];
    int t = threadIdx.x, i = blockIdx.x * 256 + t;
    int v = (i < N) ? deg[i] : 0;
    sh[t] = v;
    __syncthreads();
    for (int o = 1; o < 256; o <<= 1) {
        int tmp = (t >= o) ? sh[t - o] : 0;
        __syncthreads();
        sh[t] += tmp;
        __syncthreads();
    }
    if (i < N) {
        int excl = sh[t] - v + part[blockIdx.x];
        offs[i] = excl;
        cur[i] = excl;
    }
}
__global__ void k_scatter(const int* __restrict__ src, const int* __restrict__ dst,
                          int* __restrict__ cur, int* __restrict__ adj, int E) {
    int e = blockIdx.x * blockDim.x + threadIdx.x;
    if (e >= E) return;
    int slot = atomicAdd(&cur[dst[e]], 1);
    adj[slot] = src[e];
}

// ---------------- fused per-dst GAT + mean + relu + residual + LN ----------------
struct RelArg {
    const __hip_bfloat16* hs; // concat buffer of source type
    int hstride;              // row stride (elements)
    int hoff;                 // column offset within concat
    const float* als;
    const float* ald;
    const int* adj;
    const int* off;
    const int* deg;
    const float* bias;
};

__global__ __launch_bounds__(128) void k_dst(RelArg r0, RelArg r1, RelArg r2, int nrel,
                                             float inv_nrel, float* __restrict__ x,
                                             __hip_bfloat16* __restrict__ xb,
                                             const float* __restrict__ ln_s,
                                             const float* __restrict__ ln_b, int N) {
    __shared__ float wcache[CAP][4];
    __shared__ int scache[CAP];
    __shared__ float red[128];
    __shared__ float den_sh[4];
    __shared__ float rs[2], rss[2];
    int d = blockIdx.x;
    int t = threadIdx.x; // 128
    int c = t;
    int h1 = t & 3;
    int h2 = t >> 5;
    float xv = x[(size_t)d * HID + c];
    float relsum = 0.f;
    for (int rr = 0; rr < nrel; ++rr) {
        const RelArg& R = (rr == 0) ? r0 : (rr == 1) ? r1 : r2;
        int base = R.off[d];
        int dg = R.deg[d];
        __syncthreads(); // protect caches from previous relation's readers
        // phase 1: per-head denominator + weight cache
        float ald1 = R.ald[d * NHEAD + h1];
        float denp = 0.f;
        for (int k = (t >> 2); k < dg; k += 32) {
            int s = R.adj[base + k];
            float a = R.als[s * NHEAD + h1] + ald1;
            a = (a > 0.f) ? a : 0.2f * a;
            float w = __expf(a);
            if (k < CAP) {
                wcache[k][h1] = w;
                if (h1 == 0) scache[k] = s;
            }
            denp += w;
        }
        red[t] = denp;
        __syncthreads();
        if (t < 4) {
            float s = 0.f;
            for (int j = 0; j < 32; ++j) s += red[t + 4 * j];
            den_sh[t] = s;
        }
        __syncthreads();
        // phase 2: weighted gather, 4-deep unrolled cached path (independent loads)
        const __hip_bfloat16* hp = R.hs + R.hoff + c;
        int hstr = R.hstride;
        float acc = 0.f;
        int kc = (dg < CAP) ? dg : CAP;
        int k = 0;
        for (; k + 4 <= kc; k += 4) {
            int s0 = scache[k], s1 = scache[k + 1], s2 = scache[k + 2], s3 = scache[k + 3];
            float w0 = wcache[k][h2], w1 = wcache[k + 1][h2];
            float w2 = wcache[k + 2][h2], w3 = wcache[k + 3][h2];
            float v0 = __bfloat162float(hp[(size_t)s0 * hstr]);
            float v1 = __bfloat162float(hp[(size_t)s1 * hstr]);
            float v2 = __bfloat162float(hp[(size_t)s2 * hstr]);
            float v3 = __bfloat162float(hp[(size_t)s3 * hstr]);
            acc += w0 * v0 + w1 * v1 + w2 * v2 + w3 * v3;
        }
        for (; k < kc; ++k) {
            acc += wcache[k][h2] * __bfloat162float(hp[(size_t)scache[k] * hstr]);
        }
        float ald2 = R.ald[d * NHEAD + h2];
        for (; k < dg; ++k) { // overflow fallback (deg > CAP)
            int s = R.adj[base + k];
            float a = R.als[s * NHEAD + h2] + ald2;
            a = (a > 0.f) ? a : 0.2f * a;
            acc += __expf(a) * __bfloat162float(hp[(size_t)s * hstr]);
        }
        relsum += acc / (den_sh[h2] + 1e-16f) + R.bias[c];
    }
    float v = relsum * inv_nrel;
    v = (v > 0.f) ? v : 0.f;
    v += xv;
    // block LayerNorm over 128 channels
    float s = v, ss = v * v;
#pragma unroll
    for (int o = 32; o; o >>= 1) { s += __shfl_down(s, o); ss += __shfl_down(ss, o); }
    int wid = t >> 6, lane = t & 63;
    if (lane == 0) { rs[wid] = s; rss[wid] = ss; }
    __syncthreads();
    float S = rs[0] + rs[1], SS = rss[0] + rss[1];
    float mu = S * (1.f / HID);
    float var = SS * (1.f / HID) - mu * mu;
    float rstd = rsqrtf(var + 1e-5f);
    float o = (v - mu) * rstd * ln_s[c] + ln_b[c];
    x[(size_t)d * HID + c] = o;
    xb[(size_t)d * HID + c] = __float2bfloat16(o);
}

// ---------------- pooling: chunked segment sums (sorted batch idx) ----------------
__global__ void k_pool_part(const float* __restrict__ x, const int* __restrict__ b,
                            int N, int toff, float* __restrict__ out) {
    int r0 = blockIdx.x * 512;
    if (r0 >= N) return;
    int rend = min(r0 + 512, N);
    int c = threadIdx.x; // 128
    int cur = b[r0];
    float acc = 0.f;
    for (int i = r0; i < rend; ++i) {
        int g = b[i];
        if (g != cur) {
            atomicAdd(&out[cur * 512 + toff + c], acc);
            acc = 0.f;
            cur = g;
        }
        acc += x[(size_t)i * HID + c];
    }
    atomicAdd(&out[cur * 512 + toff + c], acc);
}
__global__ void k_cnt(const int* __restrict__ b0, const int* __restrict__ b1,
                      const int* __restrict__ b2, const int* __restrict__ b3,
                      int N0, int N1, int N2, int N3, float* __restrict__ cnt) {
    int i = blockIdx.x * blockDim.x + threadIdx.x;
    if (i >= 256) return;
    int t = i >> 6, g = i & 63;
    const int* b = (t == 0) ? b0 : (t == 1) ? b1 : (t == 2) ? b2 : b3;
    int N = (t == 0) ? N0 : (t == 1) ? N1 : (t == 2) ? N2 : N3;
    int lo = 0, hi = N;
    while (lo < hi) { int m = (lo + hi) >> 1; if (b[m] < g) lo = m + 1; else hi = m; }
    int s = lo;
    hi = N;
    while (lo < hi) { int m = (lo + hi) >> 1; if (b[m] < g + 1) lo = m + 1; else hi = m; }
    cnt[i] = (float)(lo - s);
}
__global__ void k_div(float* __restrict__ out, const float* __restrict__ cnt) {
    int idx = blockIdx.x * blockDim.x + threadIdx.x;
    if (idx >= NGRAPH * 512) return;
    int g = idx >> 9, c = idx & 511, t = c >> 7;
    out[idx] = out[idx] / fmaxf(cnt[t * NGRAPH + g], 1.0f);
}

extern "C" void kernel_launch(void* const* d_in, const int* in_sizes, int n_in,
                              void* d_out, int out_size, void* d_ws, size_t ws_size,
                              hipStream_t stream) {
    const float* x_in[4] = {(const float*)d_in[0], (const float*)d_in[1],
                            (const float*)d_in[2], (const float*)d_in[3]};
    const float* Wp[4] = {(const float*)d_in[4], (const float*)d_in[6],
                          (const float*)d_in[8], (const float*)d_in[10]};
    const float* bp[4] = {(const float*)d_in[5], (const float*)d_in[7],
                          (const float*)d_in[9], (const float*)d_in[11]};
    const float* gat_W  = (const float*)d_in[12];
    const float* gat_as = (const float*)d_in[13];
    const float* gat_ad = (const float*)d_in[14];
    const float* gat_b  = (const float*)d_in[15];
    const float* ln_s   = (const float*)d_in[16];
    const float* ln_b   = (const float*)d_in[17];
    const int* esrc[8] = {(const int*)d_in[18], (const int*)d_in[20], (const int*)d_in[22],
                          (const int*)d_in[24], (const int*)d_in[26], (const int*)d_in[28],
                          (const int*)d_in[30], (const int*)d_in[32]};
    const int* edst[8] = {(const int*)d_in[19], (const int*)d_in[21], (const int*)d_in[23],
                          (const int*)d_in[25], (const int*)d_in[27], (const int*)d_in[29],
                          (const int*)d_in[31], (const int*)d_in[33]};
    const int* bidx[4] = {(const int*)d_in[34], (const int*)d_in[35],
                          (const int*)d_in[36], (const int*)d_in[37]};
    int E[8];
    {
        const int eidx[8] = {18, 20, 22, 24, 26, 28, 30, 32};
        for (int r = 0; r < 8; ++r) E[r] = in_sizes[eidx[r]];
    }
    const int Kin[4] = {8, 10, 7, 3};
    int N[4];
    for (int t = 0; t < 4; ++t) N[t] = in_sizes[t] / Kin[t];
    const int rel_st[8] = {0, 1, 0, 2, 0, 0, 1, 2};
    const int rel_dt[8] = {1, 0, 2, 0, 3, 0, 3, 3};
    // concat col offsets within source-type group; group strides
    const int rel_hoff[8] = {0, 0, 128, 0, 256, 384, 128, 128};
    const int grp_stride[4] = {512, 256, 256, 0}; // by source type (f never source)
    (void)ws_size; (void)n_in;

    // ---- workspace carve-up ----
    char* wbase = (char*)d_ws;
    size_t cur = 0;
    auto alloc = [&](size_t bytes) -> void* {
        void* p = wbase + cur;
        cur += (bytes + 15) & ~(size_t)15;
        return p;
    };
    float* x[4];
    __hip_bfloat16* xb[4];
    for (int t = 0; t < 4; ++t) x[t] = (float*)alloc((size_t)N[t] * HID * 4);
    for (int t = 0; t < 4; ++t) xb[t] = (__hip_bfloat16*)alloc((size_t)N[t] * HID * 2);
    __hip_bfloat16* hs_g[3]; // concat hs per source type: b 512, s 256, c 256 cols
    hs_g[0] = (__hip_bfloat16*)alloc((size_t)N[0] * 512 * 2);
    hs_g[1] = (__hip_bfloat16*)alloc((size_t)N[1] * 256 * 2);
    hs_g[2] = (__hip_bfloat16*)alloc((size_t)N[2] * 256 * 2);
    __hip_bfloat16* Wsw = (__hip_bfloat16*)alloc((size_t)2 * 131072 * 2);
    float* vecall = (float*)alloc((size_t)2 * 16 * 512 * 4);
    float *als_[8], *ald_[8];
    int *deg[8], *offs[8], *curs[8], *adj[8];
    for (int r = 0; r < 8; ++r) {
        int Ns = N[rel_st[r]], Nd = N[rel_dt[r]];
        als_[r] = (float*)alloc((size_t)Ns * NHEAD * 4);
        ald_[r] = (float*)alloc((size_t)Nd * NHEAD * 4);
        deg[r]  = (int*)alloc((size_t)Nd * 4);
        offs[r] = (int*)alloc((size_t)Nd * 4);
        curs[r] = (int*)alloc((size_t)Nd * 4);
        adj[r]  = (int*)alloc((size_t)E[r] * 4);
    }
    int* part   = (int*)alloc(512 * 4);
    float* cntf = (float*)alloc(256 * 4);

    // ---- 0. CSR build + weight prep ----
    for (int r = 0; r < 8; ++r) {
        int Nd = N[rel_dt[r]];
        int nparts = (Nd + 255) / 256;
        hipMemsetAsync(deg[r], 0, (size_t)Nd * 4, stream);
        k_hist<<<(E[r] + 255) / 256, 256, 0, stream>>>(edst[r], deg[r], E[r]);
        k_scan_part<<<nparts, 256, 0, stream>>>(deg[r], part, Nd);
        k_scan_top<<<1, 512, 0, stream>>>(part, nparts);
        k_scan_down<<<nparts, 256, 0, stream>>>(deg[r], part, offs[r], curs[r], Nd);
        k_scatter<<<(E[r] + 255) / 256, 256, 0, stream>>>(esrc[r], edst[r], curs[r], adj[r], E[r]);
    }
    k_castW<<<(262144 + 255) / 256, 256, 0, stream>>>(gat_W, Wsw);
    k_mkvec<<<(16384 + 255) / 256, 256, 0, stream>>>(gat_W, gat_as, gat_ad, vecall);

    // ---- 1. input projections ----
    for (int t = 0; t < 4; ++t)
        k_proj<<<(N[t] * HID + 255) / 256, 256, 0, stream>>>(x_in[t], Wp[t], bp[t], x[t], xb[t], N[t], Kin[t]);

    // ---- 2. layers ----
    const size_t g_off[3] = {0, 65536, 98304};
    const int g_ncols[3] = {512, 256, 256};
    for (int l = 0; l < 2; ++l) {
        // 2a. hs GEMMs (per source type group)
        for (int g = 0; g < 3; ++g) {
            dim3 grid((N[g] + 63) / 64, g_ncols[g] / 128);
            k_gemm<<<grid, 256, 0, stream>>>(xb[g], Wsw + (size_t)l * 131072 + g_off[g],
                                             hs_g[g], N[g], g_ncols[g]);
        }
        // 2b. logits per type
        const float* vl = vecall + (size_t)l * 16 * 512;
        auto vvec = [&](int r, int side) { return vl + (size_t)(r * 2 + side) * 512; };
        {
            LogitPack P{};
            // type b: src rels 0,2,4,5 ; dst rels 1,3,5
            P.vec[0] = vvec(0, 0); P.out[0] = als_[0];
            P.vec[1] = vvec(2, 0); P.out[1] = als_[2];
            P.vec[2] = vvec(4, 0); P.out[2] = als_[4];
            P.vec[3] = vvec(5, 0); P.out[3] = als_[5];
            P.vec[4] = vvec(1, 1); P.out[4] = ald_[1];
            P.vec[5] = vvec(3, 1); P.out[5] = ald_[3];
            P.vec[6] = vvec(5, 1); P.out[6] = ald_[5];
            k_logits<<<(N[0] + 63) / 64, 256, 0, stream>>>(x[0], N[0], 7, P);
        }
        {
            LogitPack P{};
            P.vec[0] = vvec(1, 0); P.out[0] = als_[1];
            P.vec[1] = vvec(6, 0); P.out[1] = als_[6];
            P.vec[2] = vvec(0, 1); P.out[2] = ald_[0];
            k_logits<<<(N[1] + 63) / 64, 256, 0, stream>>>(x[1], N[1], 3, P);
        }
        {
            LogitPack P{};
            P.vec[0] = vvec(3, 0); P.out[0] = als_[3];
            P.vec[1] = vvec(7, 0); P.out[1] = als_[7];
            P.vec[2] = vvec(2, 1); P.out[2] = ald_[2];
            k_logits<<<(N[2] + 63) / 64, 256, 0, stream>>>(x[2], N[2], 3, P);
        }
        {
            LogitPack P{};
            P.vec[0] = vvec(4, 1); P.out[0] = ald_[4];
            P.vec[1] = vvec(6, 1); P.out[1] = ald_[6];
            P.vec[2] = vvec(7, 1); P.out[2] = ald_[7];
            k_logits<<<(N[3] + 63) / 64, 256, 0, stream>>>(x[3], N[3], 3, P);
        }
        // 2c. per-dst aggregation + finalize
        auto mk = [&](int r) {
            RelArg a;
            int st = rel_st[r];
            a.hs = hs_g[st]; a.hstride = grp_stride[st]; a.hoff = rel_hoff[r];
            a.als = als_[r]; a.ald = ald_[r];
            a.adj = adj[r]; a.off = offs[r]; a.deg = deg[r];
            a.bias = gat_b + (size_t)(l * 8 + r) * HID;
            return a;
        };
        const float* ls = ln_s + l * HID;
        const float* lb = ln_b + l * HID;
        k_dst<<<N[0], 128, 0, stream>>>(mk(1), mk(3), mk(5), 3, 1.f / 3.f, x[0], xb[0], ls, lb, N[0]);
        k_dst<<<N[1], 128, 0, stream>>>(mk(0), mk(0), mk(0), 1, 1.f, x[1], xb[1], ls, lb, N[1]);
        k_dst<<<N[2], 128, 0, stream>>>(mk(2), mk(2), mk(2), 1, 1.f, x[2], xb[2], ls, lb, N[2]);
        k_dst<<<N[3], 128, 0, stream>>>(mk(4), mk(6), mk(7), 3, 1.f / 3.f, x[3], xb[3], ls, lb, N[3]);
    }

    // ---- 3. pooling ----
    hipMemsetAsync(d_out, 0, (size_t)out_size * 4, stream);
    k_cnt<<<1, 256, 0, stream>>>(bidx[0], bidx[1], bidx[2], bidx[3],
                                 N[0], N[1], N[2], N[3], cntf);
    for (int t = 0; t < 4; ++t)
        k_pool_part<<<(N[t] + 511) / 512, 128, 0, stream>>>(x[t], bidx[t], N[t], t * HID, (float*)d_out);
    k_div<<<(NGRAPH * 512 + 255) / 256, 256, 0, stream>>>((float*)d_out, cntf);
}

// Round 5
// 2382.312 us; speedup vs baseline: 2.4190x; 1.3258x over previous
//
#include <hip/hip_runtime.h>
#include <hip/hip_bf16.h>
#include <cstdint>

#define HID 128
#define NHEAD 4
#define NGRAPH 64
#define CAP 512

typedef __attribute__((ext_vector_type(8))) short bf16x8;
typedef __attribute__((ext_vector_type(4))) float f32x4;

// ---------------- projection: out[N,128] = x[N,K] @ Wp[K,128] + bp (fp32 + bf16 copies) ----------------
__global__ void k_proj(const float* __restrict__ x, const float* __restrict__ Wp,
                       const float* __restrict__ bp, float* __restrict__ out,
                       __hip_bfloat16* __restrict__ outb, int N, int K) {
    int idx = blockIdx.x * blockDim.x + threadIdx.x;
    if (idx >= N * HID) return;
    int row = idx >> 7, c = idx & 127;
    float acc = bp[c];
    for (int k = 0; k < K; ++k) acc += x[row * K + k] * Wp[k * HID + c];
    out[idx] = acc;
    outb[idx] = __float2bfloat16(acc);
}

// ---------------- cast+swizzle W into per-(layer,group) concatenated bf16, MFMA-B-friendly ----------------
// dest element (k,n) at ((k>>3)*Ncols + n)*8 + (k&7)
__global__ void k_castW(const float* __restrict__ gat_W, __hip_bfloat16* __restrict__ Wsw) {
    int idx = blockIdx.x * blockDim.x + threadIdx.x; // 2*128*1024
    if (idx >= 262144) return;
    int l = idx >> 17;
    int rem = idx & 131071;
    int k = rem >> 10;
    int gc = rem & 1023;
    int rel, n, gobase, Ncols;
    if (gc < 512) {
        int i = gc >> 7;
        rel = (i == 0) ? 0 : (i == 1) ? 2 : (i == 2) ? 4 : 5;
        n = gc; gobase = 0; Ncols = 512;
    } else if (gc < 768) {
        int c2 = gc - 512;
        rel = (c2 >> 7) ? 6 : 1;
        n = c2; gobase = 65536; Ncols = 256;
    } else {
        int c2 = gc - 768;
        rel = (c2 >> 7) ? 7 : 3;
        n = c2; gobase = 98304; Ncols = 256;
    }
    int nl = n & 127;
    float v = gat_W[(((size_t)l * 8 + rel) * 128 + k) * 128 + nl];
    size_t dst = (size_t)l * 131072 + gobase + ((size_t)(k >> 3) * Ncols + n) * 8 + (k & 7);
    Wsw[dst] = __float2bfloat16(v);
}

// ---------------- vecall[l][r*2+side][k][h] = sum_j W[l,r,k,h*32+j] * a[l,r,h*32+j] ----------------
__global__ void k_mkvec(const float* __restrict__ gat_W, const float* __restrict__ gat_as,
                        const float* __restrict__ gat_ad, float* __restrict__ vecall) {
    int idx = blockIdx.x * blockDim.x + threadIdx.x; // 2*16*128*4
    if (idx >= 16384) return;
    int h = idx & 3, k = (idx >> 2) & 127, p = (idx >> 9) & 15, l = idx >> 13;
    int r = p >> 1, side = p & 1;
    const float* W = gat_W + (((size_t)l * 8 + r) * 128 + k) * 128;
    const float* a = (side ? gat_ad : gat_as) + ((size_t)l * 8 + r) * 128;
    float s = 0.f;
#pragma unroll
    for (int j = 0; j < 32; ++j) s += W[h * 32 + j] * a[h * 32 + j];
    vecall[((size_t)l * 16 + p) * 512 + k * 4 + h] = s;
}

// ---------------- MFMA GEMM: out[M,Ncols](bf16) = A[M,128](bf16) @ Bsw ----------------
__global__ __launch_bounds__(256) void k_gemm(const __hip_bfloat16* __restrict__ Abf,
                                              const __hip_bfloat16* __restrict__ Bsw,
                                              __hip_bfloat16* __restrict__ out,
                                              int M, int Ncols) {
    __shared__ __hip_bfloat16 Alds[64][136];
    int m0 = blockIdx.x * 64;
    int n0 = blockIdx.y * 128;
    int t = threadIdx.x;
    for (int i = t; i < 1024; i += 256) {
        int row = i >> 4, ch = i & 15;
        uint4 v = make_uint4(0u, 0u, 0u, 0u);
        if (m0 + row < M) v = *(const uint4*)(Abf + ((size_t)(m0 + row) * 128 + ch * 8));
        *(uint4*)&Alds[row][ch * 8] = v;
    }
    __syncthreads();
    int w = t >> 6, l = t & 63;
    int lane16 = l & 15, q = l >> 4;
    f32x4 acc[8];
#pragma unroll
    for (int nn = 0; nn < 8; ++nn) acc[nn] = (f32x4){0.f, 0.f, 0.f, 0.f};
    const __hip_bfloat16* arow = &Alds[w * 16 + lane16][q * 8];
#pragma unroll
    for (int kk = 0; kk < 4; ++kk) {
        bf16x8 a = *(const bf16x8*)(arow + kk * 32);
#pragma unroll
        for (int nn = 0; nn < 8; ++nn) {
            size_t boff = ((size_t)(kk * 4 + q) * Ncols + (n0 + nn * 16 + lane16)) * 8;
            bf16x8 b = *(const bf16x8*)(Bsw + boff);
            acc[nn] = __builtin_amdgcn_mfma_f32_16x16x32_bf16(a, b, acc[nn], 0, 0, 0);
        }
    }
    int orow = m0 + w * 16 + q * 4;
#pragma unroll
    for (int nn = 0; nn < 8; ++nn) {
        int col = n0 + nn * 16 + lane16;
#pragma unroll
        for (int r = 0; r < 4; ++r) {
            int row = orow + r;
            if (row < M) out[(size_t)row * Ncols + col] = __float2bfloat16(acc[nn][r]);
        }
    }
}

// ---------------- fused logits: out[v][i,h] = x[i,:]·vec[v][:,h], NVEC compile-time ----------------
struct LogitPack {
    const float* vec[8];
    float* out[8];
};

template <int NVEC>
__global__ __launch_bounds__(256) void k_logits(const float* __restrict__ x, int N,
                                                LogitPack P) {
    __shared__ float vs[NVEC][128][4];
    __shared__ float xs[64][129];
    int t = threadIdx.x;
    int nb = blockIdx.x * 64;
    for (int i = t; i < NVEC * 512; i += 256) {
        int v = i >> 9, j = i & 511;
        vs[v][j >> 2][j & 3] = P.vec[v][j];
    }
    for (int i = t; i < 64 * 128; i += 256) {
        int r = i >> 7, k = i & 127;
        xs[r][k] = (nb + r < N) ? x[(size_t)(nb + r) * 128 + k] : 0.f;
    }
    __syncthreads();
    int nl = t >> 2, h = t & 3;
    int node = nb + nl;
    float acc[NVEC];
#pragma unroll
    for (int v = 0; v < NVEC; ++v) acc[v] = 0.f;
#pragma unroll 4
    for (int k = 0; k < 128; ++k) {
        float xv = xs[nl][k];
#pragma unroll
        for (int v = 0; v < NVEC; ++v) acc[v] += xv * vs[v][k][h];
    }
    if (node < N) {
#pragma unroll
        for (int v = 0; v < NVEC; ++v) P.out[v][node * 4 + h] = acc[v];
    }
}

// ---------------- CSR build ----------------
__global__ void k_hist(const int* __restrict__ dst, int* __restrict__ deg, int E) {
    int e = blockIdx.x * blockDim.x + threadIdx.x;
    if (e < E) atomicAdd(&deg[dst[e]], 1);
}
__global__ void k_scan_part(const int* __restrict__ deg, int* __restrict__ part, int N) {
    __shared__ int sh[256];
    int t = threadIdx.x, i = blockIdx.x * 256 + t;
    sh[t] = (i < N) ? deg[i] : 0;
    __syncthreads();
    for (int o = 128; o; o >>= 1) {
        if (t < o) sh[t] += sh[t + o];
        __syncthreads();
    }
    if (t == 0) part[blockIdx.x] = sh[0];
}
__global__ void k_scan_top(int* __restrict__ part, int n) {
    __shared__ int sh[512];
    int t = threadIdx.x;
    int v = (t < n) ? part[t] : 0;
    sh[t] = v;
    __syncthreads();
    for (int o = 1; o < 512; o <<= 1) {
        int tmp = (t >= o) ? sh[t - o] : 0;
        __syncthreads();
        sh[t] += tmp;
        __syncthreads();
    }
    if (t < n) part[t] = sh[t] - v;
}
__global__ void k_scan_down(const int* __restrict__ deg, const int* __restrict__ part,
                            int* __restrict__ offs, int* __restrict__ cur, int N) {
    __shared__ int sh[256];
    int t = threadIdx.x, i = blockIdx.x * 256 + t;
    int v = (i < N) ? deg[i] : 0;
    sh[t] = v;
    __syncthreads();
    for (int o = 1; o < 256; o <<= 1) {
        int tmp = (t >= o) ? sh[t - o] : 0;
        __syncthreads();
        sh[t] += tmp;
        __syncthreads();
    }
    if (i < N) {
        int excl = sh[t] - v + part[blockIdx.x];
        offs[i] = excl;
        cur[i] = excl;
    }
}
__global__ void k_scatter(const int* __restrict__ src, const int* __restrict__ dst,
                          int* __restrict__ cur, int* __restrict__ adj, int E) {
    int e = blockIdx.x * blockDim.x + threadIdx.x;
    if (e >= E) return;
    int slot = atomicAdd(&cur[dst[e]], 1);
    adj[slot] = src[e];
}

// ---------------- fused per-dst GAT + mean + relu + residual + LN ----------------
struct RelArg {
    const __hip_bfloat16* hs;
    int hstride;
    int hoff;
    const float* als;
    const float* ald;
    const int* adj;
    const int* off;
    const int* deg;
    const float* bias;
};

__global__ __launch_bounds__(128) void k_dst(RelArg r0, RelArg r1, RelArg r2, int nrel,
                                             float inv_nrel, float* __restrict__ x,
                                             __hip_bfloat16* __restrict__ xb,
                                             const float* __restrict__ ln_s,
                                             const float* __restrict__ ln_b, int N) {
    __shared__ float wcache[CAP][4];
    __shared__ int scache[CAP];
    __shared__ float red[128];
    __shared__ float den_sh[4];
    __shared__ float rs[2], rss[2];
    int d = blockIdx.x;
    int t = threadIdx.x; // 128
    int c = t;
    int h1 = t & 3;
    int h2 = t >> 5;
    float xv = x[(size_t)d * HID + c];
    float relsum = 0.f;
    for (int rr = 0; rr < nrel; ++rr) {
        const RelArg& R = (rr == 0) ? r0 : (rr == 1) ? r1 : r2;
        int base = R.off[d];
        int dg = R.deg[d];
        __syncthreads();
        float ald1 = R.ald[d * NHEAD + h1];
        float denp = 0.f;
        for (int k = (t >> 2); k < dg; k += 32) {
            int s = R.adj[base + k];
            float a = R.als[s * NHEAD + h1] + ald1;
            a = (a > 0.f) ? a : 0.2f * a;
            float w = __expf(a);
            if (k < CAP) {
                wcache[k][h1] = w;
                if (h1 == 0) scache[k] = s;
            }
            denp += w;
        }
        red[t] = denp;
        __syncthreads();
        if (t < 4) {
            float s = 0.f;
            for (int j = 0; j < 32; ++j) s += red[t + 4 * j];
            den_sh[t] = s;
        }
        __syncthreads();
        const __hip_bfloat16* hp = R.hs + R.hoff + c;
        int hstr = R.hstride;
        float acc = 0.f;
        int kc = (dg < CAP) ? dg : CAP;
        int k = 0;
        for (; k + 4 <= kc; k += 4) {
            int s0 = scache[k], s1 = scache[k + 1], s2 = scache[k + 2], s3 = scache[k + 3];
            float w0 = wcache[k][h2], w1 = wcache[k + 1][h2];
            float w2 = wcache[k + 2][h2], w3 = wcache[k + 3][h2];
            float v0 = __bfloat162float(hp[(size_t)s0 * hstr]);
            float v1 = __bfloat162float(hp[(size_t)s1 * hstr]);
            float v2 = __bfloat162float(hp[(size_t)s2 * hstr]);
            float v3 = __bfloat162float(hp[(size_t)s3 * hstr]);
            acc += w0 * v0 + w1 * v1 + w2 * v2 + w3 * v3;
        }
        for (; k < kc; ++k) {
            acc += wcache[k][h2] * __bfloat162float(hp[(size_t)scache[k] * hstr]);
        }
        float ald2 = R.ald[d * NHEAD + h2];
        for (; k < dg; ++k) {
            int s = R.adj[base + k];
            float a = R.als[s * NHEAD + h2] + ald2;
            a = (a > 0.f) ? a : 0.2f * a;
            acc += __expf(a) * __bfloat162float(hp[(size_t)s * hstr]);
        }
        relsum += acc / (den_sh[h2] + 1e-16f) + R.bias[c];
    }
    float v = relsum * inv_nrel;
    v = (v > 0.f) ? v : 0.f;
    v += xv;
    float s = v, ss = v * v;
#pragma unroll
    for (int o = 32; o; o >>= 1) { s += __shfl_down(s, o); ss += __shfl_down(ss, o); }
    int wid = t >> 6, lane = t & 63;
    if (lane == 0) { rs[wid] = s; rss[wid] = ss; }
    __syncthreads();
    float S = rs[0] + rs[1], SS = rss[0] + rss[1];
    float mu = S * (1.f / HID);
    float var = SS * (1.f / HID) - mu * mu;
    float rstd = rsqrtf(var + 1e-5f);
    float o = (v - mu) * rstd * ln_s[c] + ln_b[c];
    x[(size_t)d * HID + c] = o;
    xb[(size_t)d * HID + c] = __float2bfloat16(o);
}

// ---------------- pooling ----------------
__global__ void k_pool_part(const float* __restrict__ x, const int* __restrict__ b,
                            int N, int toff, float* __restrict__ out) {
    int r0 = blockIdx.x * 512;
    if (r0 >= N) return;
    int rend = min(r0 + 512, N);
    int c = threadIdx.x; // 128
    int cur = b[r0];
    float acc = 0.f;
    for (int i = r0; i < rend; ++i) {
        int g = b[i];
        if (g != cur) {
            atomicAdd(&out[cur * 512 + toff + c], acc);
            acc = 0.f;
            cur = g;
        }
        acc += x[(size_t)i * HID + c];
    }
    atomicAdd(&out[cur * 512 + toff + c], acc);
}
__global__ void k_cnt(const int* __restrict__ b0, const int* __restrict__ b1,
                      const int* __restrict__ b2, const int* __restrict__ b3,
                      int N0, int N1, int N2, int N3, float* __restrict__ cnt) {
    int i = blockIdx.x * blockDim.x + threadIdx.x;
    if (i >= 256) return;
    int t = i >> 6, g = i & 63;
    const int* b = (t == 0) ? b0 : (t == 1) ? b1 : (t == 2) ? b2 : b3;
    int N = (t == 0) ? N0 : (t == 1) ? N1 : (t == 2) ? N2 : N3;
    int lo = 0, hi = N;
    while (lo < hi) { int m = (lo + hi) >> 1; if (b[m] < g) lo = m + 1; else hi = m; }
    int s = lo;
    hi = N;
    while (lo < hi) { int m = (lo + hi) >> 1; if (b[m] < g + 1) lo = m + 1; else hi = m; }
    cnt[i] = (float)(lo - s);
}
__global__ void k_div(float* __restrict__ out, const float* __restrict__ cnt) {
    int idx = blockIdx.x * blockDim.x + threadIdx.x;
    if (idx >= NGRAPH * 512) return;
    int g = idx >> 9, c = idx & 511, t = c >> 7;
    out[idx] = out[idx] / fmaxf(cnt[t * NGRAPH + g], 1.0f);
}

extern "C" void kernel_launch(void* const* d_in, const int* in_sizes, int n_in,
                              void* d_out, int out_size, void* d_ws, size_t ws_size,
                              hipStream_t stream) {
    const float* x_in[4] = {(const float*)d_in[0], (const float*)d_in[1],
                            (const float*)d_in[2], (const float*)d_in[3]};
    const float* Wp[4] = {(const float*)d_in[4], (const float*)d_in[6],
                          (const float*)d_in[8], (const float*)d_in[10]};
    const float* bp[4] = {(const float*)d_in[5], (const float*)d_in[7],
                          (const float*)d_in[9], (const float*)d_in[11]};
    const float* gat_W  = (const float*)d_in[12];
    const float* gat_as = (const float*)d_in[13];
    const float* gat_ad = (const float*)d_in[14];
    const float* gat_b  = (const float*)d_in[15];
    const float* ln_s   = (const float*)d_in[16];
    const float* ln_b   = (const float*)d_in[17];
    const int* esrc[8] = {(const int*)d_in[18], (const int*)d_in[20], (const int*)d_in[22],
                          (const int*)d_in[24], (const int*)d_in[26], (const int*)d_in[28],
                          (const int*)d_in[30], (const int*)d_in[32]};
    const int* edst[8] = {(const int*)d_in[19], (const int*)d_in[21], (const int*)d_in[23],
                          (const int*)d_in[25], (const int*)d_in[27], (const int*)d_in[29],
                          (const int*)d_in[31], (const int*)d_in[33]};
    const int* bidx[4] = {(const int*)d_in[34], (const int*)d_in[35],
                          (const int*)d_in[36], (const int*)d_in[37]};
    int E[8];
    {
        const int eidx[8] = {18, 20, 22, 24, 26, 28, 30, 32};
        for (int r = 0; r < 8; ++r) E[r] = in_sizes[eidx[r]];
    }
    const int Kin[4] = {8, 10, 7, 3};
    int N[4];
    for (int t = 0; t < 4; ++t) N[t] = in_sizes[t] / Kin[t];
    const int rel_st[8] = {0, 1, 0, 2, 0, 0, 1, 2};
    const int rel_dt[8] = {1, 0, 2, 0, 3, 0, 3, 3};
    const int rel_hoff[8] = {0, 0, 128, 0, 256, 384, 128, 128};
    const int grp_stride[4] = {512, 256, 256, 0};
    (void)ws_size; (void)n_in;

    // ---- workspace carve-up ----
    char* wbase = (char*)d_ws;
    size_t cur = 0;
    auto alloc = [&](size_t bytes) -> void* {
        void* p = wbase + cur;
        cur += (bytes + 15) & ~(size_t)15;
        return p;
    };
    float* x[4];
    __hip_bfloat16* xb[4];
    for (int t = 0; t < 4; ++t) x[t] = (float*)alloc((size_t)N[t] * HID * 4);
    for (int t = 0; t < 4; ++t) xb[t] = (__hip_bfloat16*)alloc((size_t)N[t] * HID * 2);
    __hip_bfloat16* hs_g[3];
    hs_g[0] = (__hip_bfloat16*)alloc((size_t)N[0] * 512 * 2);
    hs_g[1] = (__hip_bfloat16*)alloc((size_t)N[1] * 256 * 2);
    hs_g[2] = (__hip_bfloat16*)alloc((size_t)N[2] * 256 * 2);
    __hip_bfloat16* Wsw = (__hip_bfloat16*)alloc((size_t)2 * 131072 * 2);
    float* vecall = (float*)alloc((size_t)2 * 16 * 512 * 4);
    float *als_[8], *ald_[8];
    int *deg[8], *offs[8], *curs[8], *adj[8];
    for (int r = 0; r < 8; ++r) {
        int Ns = N[rel_st[r]], Nd = N[rel_dt[r]];
        als_[r] = (float*)alloc((size_t)Ns * NHEAD * 4);
        ald_[r] = (float*)alloc((size_t)Nd * NHEAD * 4);
        deg[r]  = (int*)alloc((size_t)Nd * 4);
        offs[r] = (int*)alloc((size_t)Nd * 4);
        curs[r] = (int*)alloc((size_t)Nd * 4);
        adj[r]  = (int*)alloc((size_t)E[r] * 4);
    }
    int* part   = (int*)alloc(512 * 4);
    float* cntf = (float*)alloc(256 * 4);

    // ---- 0. CSR build + weight prep ----
    for (int r = 0; r < 8; ++r) {
        int Nd = N[rel_dt[r]];
        int nparts = (Nd + 255) / 256;
        hipMemsetAsync(deg[r], 0, (size_t)Nd * 4, stream);
        k_hist<<<(E[r] + 255) / 256, 256, 0, stream>>>(edst[r], deg[r], E[r]);
        k_scan_part<<<nparts, 256, 0, stream>>>(deg[r], part, Nd);
        k_scan_top<<<1, 512, 0, stream>>>(part, nparts);
        k_scan_down<<<nparts, 256, 0, stream>>>(deg[r], part, offs[r], curs[r], Nd);
        k_scatter<<<(E[r] + 255) / 256, 256, 0, stream>>>(esrc[r], edst[r], curs[r], adj[r], E[r]);
    }
    k_castW<<<(262144 + 255) / 256, 256, 0, stream>>>(gat_W, Wsw);
    k_mkvec<<<(16384 + 255) / 256, 256, 0, stream>>>(gat_W, gat_as, gat_ad, vecall);

    // ---- 1. input projections ----
    for (int t = 0; t < 4; ++t)
        k_proj<<<(N[t] * HID + 255) / 256, 256, 0, stream>>>(x_in[t], Wp[t], bp[t], x[t], xb[t], N[t], Kin[t]);

    // ---- 2. layers ----
    const size_t g_off[3] = {0, 65536, 98304};
    const int g_ncols[3] = {512, 256, 256};
    for (int l = 0; l < 2; ++l) {
        for (int g = 0; g < 3; ++g) {
            dim3 grid((N[g] + 63) / 64, g_ncols[g] / 128);
            k_gemm<<<grid, 256, 0, stream>>>(xb[g], Wsw + (size_t)l * 131072 + g_off[g],
                                             hs_g[g], N[g], g_ncols[g]);
        }
        const float* vl = vecall + (size_t)l * 16 * 512;
        auto vvec = [&](int r, int side) { return vl + (size_t)(r * 2 + side) * 512; };
        {
            LogitPack P{};
            P.vec[0] = vvec(0, 0); P.out[0] = als_[0];
            P.vec[1] = vvec(2, 0); P.out[1] = als_[2];
            P.vec[2] = vvec(4, 0); P.out[2] = als_[4];
            P.vec[3] = vvec(5, 0); P.out[3] = als_[5];
            P.vec[4] = vvec(1, 1); P.out[4] = ald_[1];
            P.vec[5] = vvec(3, 1); P.out[5] = ald_[3];
            P.vec[6] = vvec(5, 1); P.out[6] = ald_[5];
            k_logits<7><<<(N[0] + 63) / 64, 256, 0, stream>>>(x[0], N[0], P);
        }
        {
            LogitPack P{};
            P.vec[0] = vvec(1, 0); P.out[0] = als_[1];
            P.vec[1] = vvec(6, 0); P.out[1] = als_[6];
            P.vec[2] = vvec(0, 1); P.out[2] = ald_[0];
            k_logits<3><<<(N[1] + 63) / 64, 256, 0, stream>>>(x[1], N[1], P);
        }
        {
            LogitPack P{};
            P.vec[0] = vvec(3, 0); P.out[0] = als_[3];
            P.vec[1] = vvec(7, 0); P.out[1] = als_[7];
            P.vec[2] = vvec(2, 1); P.out[2] = ald_[2];
            k_logits<3><<<(N[2] + 63) / 64, 256, 0, stream>>>(x[2], N[2], P);
        }
        {
            LogitPack P{};
            P.vec[0] = vvec(4, 1); P.out[0] = ald_[4];
            P.vec[1] = vvec(6, 1); P.out[1] = ald_[6];
            P.vec[2] = vvec(7, 1); P.out[2] = ald_[7];
            k_logits<3><<<(N[3] + 63) / 64, 256, 0, stream>>>(x[3], N[3], P);
        }
        auto mk = [&](int r) {
            RelArg a;
            int st = rel_st[r];
            a.hs = hs_g[st]; a.hstride = grp_stride[st]; a.hoff = rel_hoff[r];
            a.als = als_[r]; a.ald = ald_[r];
            a.adj = adj[r]; a.off = offs[r]; a.deg = deg[r];
            a.bias = gat_b + (size_t)(l * 8 + r) * HID;
            return a;
        };
        const float* ls = ln_s + l * HID;
        const float* lb = ln_b + l * HID;
        k_dst<<<N[0], 128, 0, stream>>>(mk(1), mk(3), mk(5), 3, 1.f / 3.f, x[0], xb[0], ls, lb, N[0]);
        k_dst<<<N[1], 128, 0, stream>>>(mk(0), mk(0), mk(0), 1, 1.f, x[1], xb[1], ls, lb, N[1]);
        k_dst<<<N[2], 128, 0, stream>>>(mk(2), mk(2), mk(2), 1, 1.f, x[2], xb[2], ls, lb, N[2]);
        k_dst<<<N[3], 128, 0, stream>>>(mk(4), mk(6), mk(7), 3, 1.f / 3.f, x[3], xb[3], ls, lb, N[3]);
    }

    // ---- 3. pooling ----
    hipMemsetAsync(d_out, 0, (size_t)out_size * 4, stream);
    k_cnt<<<1, 256, 0, stream>>>(bidx[0], bidx[1], bidx[2], bidx[3],
                                 N[0], N[1], N[2], N[3], cntf);
    for (int t = 0; t < 4; ++t)
        k_pool_part<<<(N[t] + 511) / 512, 128, 0, stream>>>(x[t], bidx[t], N[t], t * HID, (float*)d_out);
    k_div<<<(NGRAPH * 512 + 255) / 256, 256, 0, stream>>>((float*)d_out, cntf);
}

// Round 6
// 2125.903 us; speedup vs baseline: 2.7108x; 1.1206x over previous
//
#include <hip/hip_runtime.h>
#include <hip/hip_bf16.h>
#include <cstdint>

#define HID 128
#define NHEAD 4
#define NGRAPH 64

typedef __attribute__((ext_vector_type(8))) short bf16x8;
typedef __attribute__((ext_vector_type(4))) float f32x4;

// ---------------- projection: out[N,128] = x[N,K] @ Wp[K,128] + bp (fp32 + bf16 copies) ----------------
__global__ void k_proj(const float* __restrict__ x, const float* __restrict__ Wp,
                       const float* __restrict__ bp, float* __restrict__ out,
                       __hip_bfloat16* __restrict__ outb, int N, int K) {
    int idx = blockIdx.x * blockDim.x + threadIdx.x;
    if (idx >= N * HID) return;
    int row = idx >> 7, c = idx & 127;
    float acc = bp[c];
    for (int k = 0; k < K; ++k) acc += x[row * K + k] * Wp[k * HID + c];
    out[idx] = acc;
    outb[idx] = __float2bfloat16(acc);
}

// ---------------- cast+swizzle W into per-(layer,group) concatenated bf16, MFMA-B-friendly ----------------
__global__ void k_castW(const float* __restrict__ gat_W, __hip_bfloat16* __restrict__ Wsw) {
    int idx = blockIdx.x * blockDim.x + threadIdx.x; // 2*128*1024
    if (idx >= 262144) return;
    int l = idx >> 17;
    int rem = idx & 131071;
    int k = rem >> 10;
    int gc = rem & 1023;
    int rel, n, gobase, Ncols;
    if (gc < 512) {
        int i = gc >> 7;
        rel = (i == 0) ? 0 : (i == 1) ? 2 : (i == 2) ? 4 : 5;
        n = gc; gobase = 0; Ncols = 512;
    } else if (gc < 768) {
        int c2 = gc - 512;
        rel = (c2 >> 7) ? 6 : 1;
        n = c2; gobase = 65536; Ncols = 256;
    } else {
        int c2 = gc - 768;
        rel = (c2 >> 7) ? 7 : 3;
        n = c2; gobase = 98304; Ncols = 256;
    }
    int nl = n & 127;
    float v = gat_W[(((size_t)l * 8 + rel) * 128 + k) * 128 + nl];
    size_t dst = (size_t)l * 131072 + gobase + ((size_t)(k >> 3) * Ncols + n) * 8 + (k & 7);
    Wsw[dst] = __float2bfloat16(v);
}

// ---------------- vecall[l][r*2+side][k][h] ----------------
__global__ void k_mkvec(const float* __restrict__ gat_W, const float* __restrict__ gat_as,
                        const float* __restrict__ gat_ad, float* __restrict__ vecall) {
    int idx = blockIdx.x * blockDim.x + threadIdx.x; // 2*16*128*4
    if (idx >= 16384) return;
    int h = idx & 3, k = (idx >> 2) & 127, p = (idx >> 9) & 15, l = idx >> 13;
    int r = p >> 1, side = p & 1;
    const float* W = gat_W + (((size_t)l * 8 + r) * 128 + k) * 128;
    const float* a = (side ? gat_ad : gat_as) + ((size_t)l * 8 + r) * 128;
    float s = 0.f;
#pragma unroll
    for (int j = 0; j < 32; ++j) s += W[h * 32 + j] * a[h * 32 + j];
    vecall[((size_t)l * 16 + p) * 512 + k * 4 + h] = s;
}

// ---------------- MFMA GEMM ----------------
__global__ __launch_bounds__(256) void k_gemm(const __hip_bfloat16* __restrict__ Abf,
                                              const __hip_bfloat16* __restrict__ Bsw,
                                              __hip_bfloat16* __restrict__ out,
                                              int M, int Ncols) {
    __shared__ __hip_bfloat16 Alds[64][136];
    int m0 = blockIdx.x * 64;
    int n0 = blockIdx.y * 128;
    int t = threadIdx.x;
    for (int i = t; i < 1024; i += 256) {
        int row = i >> 4, ch = i & 15;
        uint4 v = make_uint4(0u, 0u, 0u, 0u);
        if (m0 + row < M) v = *(const uint4*)(Abf + ((size_t)(m0 + row) * 128 + ch * 8));
        *(uint4*)&Alds[row][ch * 8] = v;
    }
    __syncthreads();
    int w = t >> 6, l = t & 63;
    int lane16 = l & 15, q = l >> 4;
    f32x4 acc[8];
#pragma unroll
    for (int nn = 0; nn < 8; ++nn) acc[nn] = (f32x4){0.f, 0.f, 0.f, 0.f};
    const __hip_bfloat16* arow = &Alds[w * 16 + lane16][q * 8];
#pragma unroll
    for (int kk = 0; kk < 4; ++kk) {
        bf16x8 a = *(const bf16x8*)(arow + kk * 32);
#pragma unroll
        for (int nn = 0; nn < 8; ++nn) {
            size_t boff = ((size_t)(kk * 4 + q) * Ncols + (n0 + nn * 16 + lane16)) * 8;
            bf16x8 b = *(const bf16x8*)(Bsw + boff);
            acc[nn] = __builtin_amdgcn_mfma_f32_16x16x32_bf16(a, b, acc[nn], 0, 0, 0);
        }
    }
    int orow = m0 + w * 16 + q * 4;
#pragma unroll
    for (int nn = 0; nn < 8; ++nn) {
        int col = n0 + nn * 16 + lane16;
#pragma unroll
        for (int r = 0; r < 4; ++r) {
            int row = orow + r;
            if (row < M) out[(size_t)row * Ncols + col] = __float2bfloat16(acc[nn][r]);
        }
    }
}

// ---------------- fused logits ----------------
struct LogitPack {
    const float* vec[8];
    float* out[8];
};

template <int NVEC>
__global__ __launch_bounds__(256) void k_logits(const float* __restrict__ x, int N,
                                                LogitPack P) {
    __shared__ float vs[NVEC][128][4];
    __shared__ float xs[64][129];
    int t = threadIdx.x;
    int nb = blockIdx.x * 64;
    for (int i = t; i < NVEC * 512; i += 256) {
        int v = i >> 9, j = i & 511;
        vs[v][j >> 2][j & 3] = P.vec[v][j];
    }
    for (int i = t; i < 64 * 128; i += 256) {
        int r = i >> 7, k = i & 127;
        xs[r][k] = (nb + r < N) ? x[(size_t)(nb + r) * 128 + k] : 0.f;
    }
    __syncthreads();
    int nl = t >> 2, h = t & 3;
    int node = nb + nl;
    float acc[NVEC];
#pragma unroll
    for (int v = 0; v < NVEC; ++v) acc[v] = 0.f;
#pragma unroll 4
    for (int k = 0; k < 128; ++k) {
        float xv = xs[nl][k];
#pragma unroll
        for (int v = 0; v < NVEC; ++v) acc[v] += xv * vs[v][k][h];
    }
    if (node < N) {
#pragma unroll
        for (int v = 0; v < NVEC; ++v) P.out[v][node * 4 + h] = acc[v];
    }
}

// ---------------- CSR build ----------------
__global__ void k_hist(const int* __restrict__ dst, int* __restrict__ deg, int E) {
    int e = blockIdx.x * blockDim.x + threadIdx.x;
    if (e < E) atomicAdd(&deg[dst[e]], 1);
}
__global__ void k_scan_part(const int* __restrict__ deg, int* __restrict__ part, int N) {
    __shared__ int sh[256];
    int t = threadIdx.x, i = blockIdx.x * 256 + t;
    sh[t] = (i < N) ? deg[i] : 0;
    __syncthreads();
    for (int o = 128; o; o >>= 1) {
        if (t < o) sh[t] += sh[t + o];
        __syncthreads();
    }
    if (t == 0) part[blockIdx.x] = sh[0];
}
__global__ void k_scan_top(int* __restrict__ part, int n) {
    __shared__ int sh[512];
    int t = threadIdx.x;
    int v = (t < n) ? part[t] : 0;
    sh[t] = v;
    __syncthreads();
    for (int o = 1; o < 512; o <<= 1) {
        int tmp = (t >= o) ? sh[t - o] : 0;
        __syncthreads();
        sh[t] += tmp;
        __syncthreads();
    }
    if (t < n) part[t] = sh[t] - v;
}
__global__ void k_scan_down(const int* __restrict__ deg, const int* __restrict__ part,
                            int* __restrict__ offs, int* __restrict__ cur, int N) {
    __shared__ int sh[256];
    int t = threadIdx.x, i = blockIdx.x * 256 + t;
    int v = (i < N) ? deg[i] : 0;
    sh[t] = v;
    __syncthreads();
    for (int o = 1; o < 256; o <<= 1) {
        int tmp = (t >= o) ? sh[t - o] : 0;
        __syncthreads();
        sh[t] += tmp;
        __syncthreads();
    }
    if (i < N) {
        int excl = sh[t] - v + part[blockIdx.x];
        offs[i] = excl;
        cur[i] = excl;
    }
}
__global__ void k_scatter(const int* __restrict__ src, const int* __restrict__ dst,
                          int* __restrict__ cur, int* __restrict__ adj, int E) {
    int e = blockIdx.x * blockDim.x + threadIdx.x;
    if (e >= E) return;
    int slot = atomicAdd(&cur[dst[e]], 1);
    adj[slot] = src[e];
}

// ---------------- fused per-dst GAT: single-pass num/den, one wave per dst ----------------
struct RelArg {
    const __hip_bfloat16* hs;
    int hstride;
    int hoff;
    const float* als;
    const float* ald;
    const int* adj;
    const int* off;
    const int* deg;
    const float* bias;
};

__device__ __forceinline__ float lrelu(float a) { return (a > 0.f) ? a : 0.2f * a; }

__global__ __launch_bounds__(256) void k_dst(RelArg r0, RelArg r1, RelArg r2, int nrel,
                                             float inv_nrel, float* __restrict__ x,
                                             __hip_bfloat16* __restrict__ xb,
                                             const float* __restrict__ ln_s,
                                             const float* __restrict__ ln_b, int N) {
    int wv = threadIdx.x >> 6, lane = threadIdx.x & 63;
    int d = blockIdx.x * 4 + wv;
    if (d >= N) return;
    int c0 = lane * 2;        // lane handles channels c0, c0+1 (same head)
    int h = lane >> 4;        // head = c0>>5
    float2 xv = *(const float2*)&x[(size_t)d * HID + c0];
    float rel0 = 0.f, rel1 = 0.f;
    for (int rr = 0; rr < nrel; ++rr) {
        const RelArg& R = (rr == 0) ? r0 : (rr == 1) ? r1 : r2;
        int base = R.off[d];
        int dg = R.deg[d];
        float aldh = R.ald[d * NHEAD + h];
        const __hip_bfloat16* hp = R.hs + R.hoff + c0;
        const int hstr = R.hstride;
        const int* ap = R.adj + base;
        float acc0 = 0.f, acc1 = 0.f, den = 0.f;
        int k = 0;
        for (; k + 4 <= dg; k += 4) {
            int s0 = ap[k], s1 = ap[k + 1], s2 = ap[k + 2], s3 = ap[k + 3];
            float w0 = __expf(lrelu(R.als[s0 * NHEAD + h] + aldh));
            float w1 = __expf(lrelu(R.als[s1 * NHEAD + h] + aldh));
            float w2 = __expf(lrelu(R.als[s2 * NHEAD + h] + aldh));
            float w3 = __expf(lrelu(R.als[s3 * NHEAD + h] + aldh));
            __hip_bfloat162 v0 = *(const __hip_bfloat162*)(hp + (size_t)s0 * hstr);
            __hip_bfloat162 v1 = *(const __hip_bfloat162*)(hp + (size_t)s1 * hstr);
            __hip_bfloat162 v2 = *(const __hip_bfloat162*)(hp + (size_t)s2 * hstr);
            __hip_bfloat162 v3 = *(const __hip_bfloat162*)(hp + (size_t)s3 * hstr);
            acc0 += w0 * __bfloat162float(v0.x) + w1 * __bfloat162float(v1.x)
                  + w2 * __bfloat162float(v2.x) + w3 * __bfloat162float(v3.x);
            acc1 += w0 * __bfloat162float(v0.y) + w1 * __bfloat162float(v1.y)
                  + w2 * __bfloat162float(v2.y) + w3 * __bfloat162float(v3.y);
            den += w0 + w1 + w2 + w3;
        }
        for (; k < dg; ++k) {
            int s = ap[k];
            float w = __expf(lrelu(R.als[s * NHEAD + h] + aldh));
            __hip_bfloat162 v = *(const __hip_bfloat162*)(hp + (size_t)s * hstr);
            acc0 += w * __bfloat162float(v.x);
            acc1 += w * __bfloat162float(v.y);
            den += w;
        }
        float inv = 1.f / (den + 1e-16f);
        rel0 += acc0 * inv + R.bias[c0];
        rel1 += acc1 * inv + R.bias[c0 + 1];
    }
    float v0 = rel0 * inv_nrel;
    float v1 = rel1 * inv_nrel;
    v0 = (v0 > 0.f) ? v0 : 0.f;
    v1 = (v1 > 0.f) ? v1 : 0.f;
    v0 += xv.x;
    v1 += xv.y;
    // wave-local LayerNorm over 128 channels (butterfly, no LDS)
    float s = v0 + v1, ss = v0 * v0 + v1 * v1;
#pragma unroll
    for (int o = 32; o; o >>= 1) {
        s += __shfl_xor(s, o);
        ss += __shfl_xor(ss, o);
    }
    float mu = s * (1.f / HID);
    float var = ss * (1.f / HID) - mu * mu;
    float rstd = rsqrtf(var + 1e-5f);
    float o0 = (v0 - mu) * rstd * ln_s[c0] + ln_b[c0];
    float o1 = (v1 - mu) * rstd * ln_s[c0 + 1] + ln_b[c0 + 1];
    *(float2*)&x[(size_t)d * HID + c0] = make_float2(o0, o1);
    __hip_bfloat162 ob;
    ob.x = __float2bfloat16(o0);
    ob.y = __float2bfloat16(o1);
    *(__hip_bfloat162*)&xb[(size_t)d * HID + c0] = ob;
}

// ---------------- pooling ----------------
__global__ void k_pool_part(const float* __restrict__ x, const int* __restrict__ b,
                            int N, int toff, float* __restrict__ out) {
    int r0 = blockIdx.x * 512;
    if (r0 >= N) return;
    int rend = min(r0 + 512, N);
    int c = threadIdx.x; // 128
    int cur = b[r0];
    float acc = 0.f;
    for (int i = r0; i < rend; ++i) {
        int g = b[i];
        if (g != cur) {
            atomicAdd(&out[cur * 512 + toff + c], acc);
            acc = 0.f;
            cur = g;
        }
        acc += x[(size_t)i * HID + c];
    }
    atomicAdd(&out[cur * 512 + toff + c], acc);
}
__global__ void k_cnt(const int* __restrict__ b0, const int* __restrict__ b1,
                      const int* __restrict__ b2, const int* __restrict__ b3,
                      int N0, int N1, int N2, int N3, float* __restrict__ cnt) {
    int i = blockIdx.x * blockDim.x + threadIdx.x;
    if (i >= 256) return;
    int t = i >> 6, g = i & 63;
    const int* b = (t == 0) ? b0 : (t == 1) ? b1 : (t == 2) ? b2 : b3;
    int N = (t == 0) ? N0 : (t == 1) ? N1 : (t == 2) ? N2 : N3;
    int lo = 0, hi = N;
    while (lo < hi) { int m = (lo + hi) >> 1; if (b[m] < g) lo = m + 1; else hi = m; }
    int s = lo;
    hi = N;
    while (lo < hi) { int m = (lo + hi) >> 1; if (b[m] < g + 1) lo = m + 1; else hi = m; }
    cnt[i] = (float)(lo - s);
}
__global__ void k_div(float* __restrict__ out, const float* __restrict__ cnt) {
    int idx = blockIdx.x * blockDim.x + threadIdx.x;
    if (idx >= NGRAPH * 512) return;
    int g = idx >> 9, c = idx & 511, t = c >> 7;
    out[idx] = out[idx] / fmaxf(cnt[t * NGRAPH + g], 1.0f);
}

extern "C" void kernel_launch(void* const* d_in, const int* in_sizes, int n_in,
                              void* d_out, int out_size, void* d_ws, size_t ws_size,
                              hipStream_t stream) {
    const float* x_in[4] = {(const float*)d_in[0], (const float*)d_in[1],
                            (const float*)d_in[2], (const float*)d_in[3]};
    const float* Wp[4] = {(const float*)d_in[4], (const float*)d_in[6],
                          (const float*)d_in[8], (const float*)d_in[10]};
    const float* bp[4] = {(const float*)d_in[5], (const float*)d_in[7],
                          (const float*)d_in[9], (const float*)d_in[11]};
    const float* gat_W  = (const float*)d_in[12];
    const float* gat_as = (const float*)d_in[13];
    const float* gat_ad = (const float*)d_in[14];
    const float* gat_b  = (const float*)d_in[15];
    const float* ln_s   = (const float*)d_in[16];
    const float* ln_b   = (const float*)d_in[17];
    const int* esrc[8] = {(const int*)d_in[18], (const int*)d_in[20], (const int*)d_in[22],
                          (const int*)d_in[24], (const int*)d_in[26], (const int*)d_in[28],
                          (const int*)d_in[30], (const int*)d_in[32]};
    const int* edst[8] = {(const int*)d_in[19], (const int*)d_in[21], (const int*)d_in[23],
                          (const int*)d_in[25], (const int*)d_in[27], (const int*)d_in[29],
                          (const int*)d_in[31], (const int*)d_in[33]};
    const int* bidx[4] = {(const int*)d_in[34], (const int*)d_in[35],
                          (const int*)d_in[36], (const int*)d_in[37]};
    int E[8];
    {
        const int eidx[8] = {18, 20, 22, 24, 26, 28, 30, 32};
        for (int r = 0; r < 8; ++r) E[r] = in_sizes[eidx[r]];
    }
    const int Kin[4] = {8, 10, 7, 3};
    int N[4];
    for (int t = 0; t < 4; ++t) N[t] = in_sizes[t] / Kin[t];
    const int rel_st[8] = {0, 1, 0, 2, 0, 0, 1, 2};
    const int rel_dt[8] = {1, 0, 2, 0, 3, 0, 3, 3};
    const int rel_hoff[8] = {0, 0, 128, 0, 256, 384, 128, 128};
    const int grp_stride[4] = {512, 256, 256, 0};
    (void)ws_size; (void)n_in;

    // ---- workspace carve-up ----
    char* wbase = (char*)d_ws;
    size_t cur = 0;
    auto alloc = [&](size_t bytes) -> void* {
        void* p = wbase + cur;
        cur += (bytes + 15) & ~(size_t)15;
        return p;
    };
    float* x[4];
    __hip_bfloat16* xb[4];
    for (int t = 0; t < 4; ++t) x[t] = (float*)alloc((size_t)N[t] * HID * 4);
    for (int t = 0; t < 4; ++t) xb[t] = (__hip_bfloat16*)alloc((size_t)N[t] * HID * 2);
    __hip_bfloat16* hs_g[3];
    hs_g[0] = (__hip_bfloat16*)alloc((size_t)N[0] * 512 * 2);
    hs_g[1] = (__hip_bfloat16*)alloc((size_t)N[1] * 256 * 2);
    hs_g[2] = (__hip_bfloat16*)alloc((size_t)N[2] * 256 * 2);
    __hip_bfloat16* Wsw = (__hip_bfloat16*)alloc((size_t)2 * 131072 * 2);
    float* vecall = (float*)alloc((size_t)2 * 16 * 512 * 4);
    float *als_[8], *ald_[8];
    int *deg[8], *offs[8], *curs[8], *adj[8];
    for (int r = 0; r < 8; ++r) {
        int Ns = N[rel_st[r]], Nd = N[rel_dt[r]];
        als_[r] = (float*)alloc((size_t)Ns * NHEAD * 4);
        ald_[r] = (float*)alloc((size_t)Nd * NHEAD * 4);
        deg[r]  = (int*)alloc((size_t)Nd * 4);
        offs[r] = (int*)alloc((size_t)Nd * 4);
        curs[r] = (int*)alloc((size_t)Nd * 4);
        adj[r]  = (int*)alloc((size_t)E[r] * 4);
    }
    int* part   = (int*)alloc(512 * 4);
    float* cntf = (float*)alloc(256 * 4);

    // ---- 0. CSR build + weight prep ----
    for (int r = 0; r < 8; ++r) {
        int Nd = N[rel_dt[r]];
        int nparts = (Nd + 255) / 256;
        hipMemsetAsync(deg[r], 0, (size_t)Nd * 4, stream);
        k_hist<<<(E[r] + 255) / 256, 256, 0, stream>>>(edst[r], deg[r], E[r]);
        k_scan_part<<<nparts, 256, 0, stream>>>(deg[r], part, Nd);
        k_scan_top<<<1, 512, 0, stream>>>(part, nparts);
        k_scan_down<<<nparts, 256, 0, stream>>>(deg[r], part, offs[r], curs[r], Nd);
        k_scatter<<<(E[r] + 255) / 256, 256, 0, stream>>>(esrc[r], edst[r], curs[r], adj[r], E[r]);
    }
    k_castW<<<(262144 + 255) / 256, 256, 0, stream>>>(gat_W, Wsw);
    k_mkvec<<<(16384 + 255) / 256, 256, 0, stream>>>(gat_W, gat_as, gat_ad, vecall);

    // ---- 1. input projections ----
    for (int t = 0; t < 4; ++t)
        k_proj<<<(N[t] * HID + 255) / 256, 256, 0, stream>>>(x_in[t], Wp[t], bp[t], x[t], xb[t], N[t], Kin[t]);

    // ---- 2. layers ----
    const size_t g_off[3] = {0, 65536, 98304};
    const int g_ncols[3] = {512, 256, 256};
    for (int l = 0; l < 2; ++l) {
        for (int g = 0; g < 3; ++g) {
            dim3 grid((N[g] + 63) / 64, g_ncols[g] / 128);
            k_gemm<<<grid, 256, 0, stream>>>(xb[g], Wsw + (size_t)l * 131072 + g_off[g],
                                             hs_g[g], N[g], g_ncols[g]);
        }
        const float* vl = vecall + (size_t)l * 16 * 512;
        auto vvec = [&](int r, int side) { return vl + (size_t)(r * 2 + side) * 512; };
        {
            LogitPack P{};
            P.vec[0] = vvec(0, 0); P.out[0] = als_[0];
            P.vec[1] = vvec(2, 0); P.out[1] = als_[2];
            P.vec[2] = vvec(4, 0); P.out[2] = als_[4];
            P.vec[3] = vvec(5, 0); P.out[3] = als_[5];
            P.vec[4] = vvec(1, 1); P.out[4] = ald_[1];
            P.vec[5] = vvec(3, 1); P.out[5] = ald_[3];
            P.vec[6] = vvec(5, 1); P.out[6] = ald_[5];
            k_logits<7><<<(N[0] + 63) / 64, 256, 0, stream>>>(x[0], N[0], P);
        }
        {
            LogitPack P{};
            P.vec[0] = vvec(1, 0); P.out[0] = als_[1];
            P.vec[1] = vvec(6, 0); P.out[1] = als_[6];
            P.vec[2] = vvec(0, 1); P.out[2] = ald_[0];
            k_logits<3><<<(N[1] + 63) / 64, 256, 0, stream>>>(x[1], N[1], P);
        }
        {
            LogitPack P{};
            P.vec[0] = vvec(3, 0); P.out[0] = als_[3];
            P.vec[1] = vvec(7, 0); P.out[1] = als_[7];
            P.vec[2] = vvec(2, 1); P.out[2] = ald_[2];
            k_logits<3><<<(N[2] + 63) / 64, 256, 0, stream>>>(x[2], N[2], P);
        }
        {
            LogitPack P{};
            P.vec[0] = vvec(4, 1); P.out[0] = ald_[4];
            P.vec[1] = vvec(6, 1); P.out[1] = ald_[6];
            P.vec[2] = vvec(7, 1); P.out[2] = ald_[7];
            k_logits<3><<<(N[3] + 63) / 64, 256, 0, stream>>>(x[3], N[3], P);
        }
        auto mk = [&](int r) {
            RelArg a;
            int st = rel_st[r];
            a.hs = hs_g[st]; a.hstride = grp_stride[st]; a.hoff = rel_hoff[r];
            a.als = als_[r]; a.ald = ald_[r];
            a.adj = adj[r]; a.off = offs[r]; a.deg = deg[r];
            a.bias = gat_b + (size_t)(l * 8 + r) * HID;
            return a;
        };
        const float* ls = ln_s + l * HID;
        const float* lb = ln_b + l * HID;
        k_dst<<<(N[0] + 3) / 4, 256, 0, stream>>>(mk(1), mk(3), mk(5), 3, 1.f / 3.f, x[0], xb[0], ls, lb, N[0]);
        k_dst<<<(N[1] + 3) / 4, 256, 0, stream>>>(mk(0), mk(0), mk(0), 1, 1.f, x[1], xb[1], ls, lb, N[1]);
        k_dst<<<(N[2] + 3) / 4, 256, 0, stream>>>(mk(2), mk(2), mk(2), 1, 1.f, x[2], xb[2], ls, lb, N[2]);
        k_dst<<<(N[3] + 3) / 4, 256, 0, stream>>>(mk(4), mk(6), mk(7), 3, 1.f / 3.f, x[3], xb[3], ls, lb, N[3]);
    }

    // ---- 3. pooling ----
    hipMemsetAsync(d_out, 0, (size_t)out_size * 4, stream);
    k_cnt<<<1, 256, 0, stream>>>(bidx[0], bidx[1], bidx[2], bidx[3],
                                 N[0], N[1], N[2], N[3], cntf);
    for (int t = 0; t < 4; ++t)
        k_pool_part<<<(N[t] + 511) / 512, 128, 0, stream>>>(x[t], bidx[t], N[t], t * HID, (float*)d_out);
    k_div<<<(NGRAPH * 512 + 255) / 256, 256, 0, stream>>>((float*)d_out, cntf);
}

// Round 7
// 1573.627 us; speedup vs baseline: 3.6622x; 1.3510x over previous
//
#include <hip/hip_runtime.h>
#include <hip/hip_bf16.h>
#include <cstdint>

#define HID 128
#define NHEAD 4
#define NGRAPH 64
#define PCHUNK 32

typedef __attribute__((ext_vector_type(8))) short bf16x8;
typedef __attribute__((ext_vector_type(4))) float f32x4;

// ---------------- projection: out[N,128] = x[N,K] @ Wp[K,128] + bp (fp32 + bf16 copies) ----------------
__global__ void k_proj(const float* __restrict__ x, const float* __restrict__ Wp,
                       const float* __restrict__ bp, float* __restrict__ out,
                       __hip_bfloat16* __restrict__ outb, int N, int K) {
    int idx = blockIdx.x * blockDim.x + threadIdx.x;
    if (idx >= N * HID) return;
    int row = idx >> 7, c = idx & 127;
    float acc = bp[c];
    for (int k = 0; k < K; ++k) acc += x[row * K + k] * Wp[k * HID + c];
    out[idx] = acc;
    outb[idx] = __float2bfloat16(acc);
}

// ---------------- cast+swizzle W into per-(layer,group) concatenated bf16, MFMA-B-friendly ----------------
__global__ void k_castW(const float* __restrict__ gat_W, __hip_bfloat16* __restrict__ Wsw) {
    int idx = blockIdx.x * blockDim.x + threadIdx.x; // 2*128*1024
    if (idx >= 262144) return;
    int l = idx >> 17;
    int rem = idx & 131071;
    int k = rem >> 10;
    int gc = rem & 1023;
    int rel, n, gobase, Ncols;
    if (gc < 512) {
        int i = gc >> 7;
        rel = (i == 0) ? 0 : (i == 1) ? 2 : (i == 2) ? 4 : 5;
        n = gc; gobase = 0; Ncols = 512;
    } else if (gc < 768) {
        int c2 = gc - 512;
        rel = (c2 >> 7) ? 6 : 1;
        n = c2; gobase = 65536; Ncols = 256;
    } else {
        int c2 = gc - 768;
        rel = (c2 >> 7) ? 7 : 3;
        n = c2; gobase = 98304; Ncols = 256;
    }
    int nl = n & 127;
    float v = gat_W[(((size_t)l * 8 + rel) * 128 + k) * 128 + nl];
    size_t dst = (size_t)l * 131072 + gobase + ((size_t)(k >> 3) * Ncols + n) * 8 + (k & 7);
    Wsw[dst] = __float2bfloat16(v);
}

// ---------------- vecall[l][r*2+side][k][h] ----------------
__global__ void k_mkvec(const float* __restrict__ gat_W, const float* __restrict__ gat_as,
                        const float* __restrict__ gat_ad, float* __restrict__ vecall) {
    int idx = blockIdx.x * blockDim.x + threadIdx.x; // 2*16*128*4
    if (idx >= 16384) return;
    int h = idx & 3, k = (idx >> 2) & 127, p = (idx >> 9) & 15, l = idx >> 13;
    int r = p >> 1, side = p & 1;
    const float* W = gat_W + (((size_t)l * 8 + r) * 128 + k) * 128;
    const float* a = (side ? gat_ad : gat_as) + ((size_t)l * 8 + r) * 128;
    float s = 0.f;
#pragma unroll
    for (int j = 0; j < 32; ++j) s += W[h * 32 + j] * a[h * 32 + j];
    vecall[((size_t)l * 16 + p) * 512 + k * 4 + h] = s;
}

// ---------------- MFMA GEMM ----------------
__global__ __launch_bounds__(256) void k_gemm(const __hip_bfloat16* __restrict__ Abf,
                                              const __hip_bfloat16* __restrict__ Bsw,
                                              __hip_bfloat16* __restrict__ out,
                                              int M, int Ncols) {
    __shared__ __hip_bfloat16 Alds[64][136];
    int m0 = blockIdx.x * 64;
    int n0 = blockIdx.y * 128;
    int t = threadIdx.x;
    for (int i = t; i < 1024; i += 256) {
        int row = i >> 4, ch = i & 15;
        uint4 v = make_uint4(0u, 0u, 0u, 0u);
        if (m0 + row < M) v = *(const uint4*)(Abf + ((size_t)(m0 + row) * 128 + ch * 8));
        *(uint4*)&Alds[row][ch * 8] = v;
    }
    __syncthreads();
    int w = t >> 6, l = t & 63;
    int lane16 = l & 15, q = l >> 4;
    f32x4 acc[8];
#pragma unroll
    for (int nn = 0; nn < 8; ++nn) acc[nn] = (f32x4){0.f, 0.f, 0.f, 0.f};
    const __hip_bfloat16* arow = &Alds[w * 16 + lane16][q * 8];
#pragma unroll
    for (int kk = 0; kk < 4; ++kk) {
        bf16x8 a = *(const bf16x8*)(arow + kk * 32);
#pragma unroll
        for (int nn = 0; nn < 8; ++nn) {
            size_t boff = ((size_t)(kk * 4 + q) * Ncols + (n0 + nn * 16 + lane16)) * 8;
            bf16x8 b = *(const bf16x8*)(Bsw + boff);
            acc[nn] = __builtin_amdgcn_mfma_f32_16x16x32_bf16(a, b, acc[nn], 0, 0, 0);
        }
    }
    int orow = m0 + w * 16 + q * 4;
#pragma unroll
    for (int nn = 0; nn < 8; ++nn) {
        int col = n0 + nn * 16 + lane16;
#pragma unroll
        for (int r = 0; r < 4; ++r) {
            int row = orow + r;
            if (row < M) out[(size_t)row * Ncols + col] = __float2bfloat16(acc[nn][r]);
        }
    }
}

// ---------------- fused logits ----------------
struct LogitPack {
    const float* vec[8];
    float* out[8];
};

template <int NVEC>
__global__ __launch_bounds__(256) void k_logits(const float* __restrict__ x, int N,
                                                LogitPack P) {
    __shared__ float vs[NVEC][128][4];
    __shared__ float xs[64][129];
    int t = threadIdx.x;
    int nb = blockIdx.x * 64;
    for (int i = t; i < NVEC * 512; i += 256) {
        int v = i >> 9, j = i & 511;
        vs[v][j >> 2][j & 3] = P.vec[v][j];
    }
    for (int i = t; i < 64 * 128; i += 256) {
        int r = i >> 7, k = i & 127;
        xs[r][k] = (nb + r < N) ? x[(size_t)(nb + r) * 128 + k] : 0.f;
    }
    __syncthreads();
    int nl = t >> 2, h = t & 3;
    int node = nb + nl;
    float acc[NVEC];
#pragma unroll
    for (int v = 0; v < NVEC; ++v) acc[v] = 0.f;
#pragma unroll 4
    for (int k = 0; k < 128; ++k) {
        float xv = xs[nl][k];
#pragma unroll
        for (int v = 0; v < NVEC; ++v) acc[v] += xv * vs[v][k][h];
    }
    if (node < N) {
#pragma unroll
        for (int v = 0; v < NVEC; ++v) P.out[v][node * 4 + h] = acc[v];
    }
}

// ---------------- CSR build ----------------
__global__ void k_hist(const int* __restrict__ dst, int* __restrict__ deg, int E) {
    int e = blockIdx.x * blockDim.x + threadIdx.x;
    if (e < E) atomicAdd(&deg[dst[e]], 1);
}
__global__ void k_scan_part(const int* __restrict__ deg, int* __restrict__ part, int N) {
    __shared__ int sh[256];
    int t = threadIdx.x, i = blockIdx.x * 256 + t;
    sh[t] = (i < N) ? deg[i] : 0;
    __syncthreads();
    for (int o = 128; o; o >>= 1) {
        if (t < o) sh[t] += sh[t + o];
        __syncthreads();
    }
    if (t == 0) part[blockIdx.x] = sh[0];
}
__global__ void k_scan_top(int* __restrict__ part, int n) {
    __shared__ int sh[512];
    int t = threadIdx.x;
    int v = (t < n) ? part[t] : 0;
    sh[t] = v;
    __syncthreads();
    for (int o = 1; o < 512; o <<= 1) {
        int tmp = (t >= o) ? sh[t - o] : 0;
        __syncthreads();
        sh[t] += tmp;
        __syncthreads();
    }
    if (t < n) part[t] = sh[t] - v;
}
__global__ void k_scan_down(const int* __restrict__ deg, const int* __restrict__ part,
                            int* __restrict__ offs, int* __restrict__ cur, int N) {
    __shared__ int sh[256];
    int t = threadIdx.x, i = blockIdx.x * 256 + t;
    int v = (i < N) ? deg[i] : 0;
    sh[t] = v;
    __syncthreads();
    for (int o = 1; o < 256; o <<= 1) {
        int tmp = (t >= o) ? sh[t - o] : 0;
        __syncthreads();
        sh[t] += tmp;
        __syncthreads();
    }
    if (i < N) {
        int excl = sh[t] - v + part[blockIdx.x];
        offs[i] = excl;
        cur[i] = excl;
    }
}
__global__ void k_scatter(const int* __restrict__ src, const int* __restrict__ dst,
                          int* __restrict__ cur, int* __restrict__ adj, int E) {
    int e = blockIdx.x * blockDim.x + threadIdx.x;
    if (e >= E) return;
    int slot = atomicAdd(&cur[dst[e]], 1);
    adj[slot] = src[e];
}

// ---------------- fused per-dst GAT: single-pass num/den, one wave per dst ----------------
struct RelArg {
    const __hip_bfloat16* hs;
    int hstride;
    int hoff;
    const float* als;
    const float* ald;
    const int* adj;
    const int* off;
    const int* deg;
    const float* bias;
};

__device__ __forceinline__ float lrelu(float a) { return (a > 0.f) ? a : 0.2f * a; }

__global__ __launch_bounds__(256) void k_dst(RelArg r0, RelArg r1, RelArg r2, int nrel,
                                             float inv_nrel, float* __restrict__ x,
                                             __hip_bfloat16* __restrict__ xb,
                                             const float* __restrict__ ln_s,
                                             const float* __restrict__ ln_b, int N) {
    int wv = threadIdx.x >> 6, lane = threadIdx.x & 63;
    int d = blockIdx.x * 4 + wv;
    if (d >= N) return;
    int c0 = lane * 2;        // lane handles channels c0, c0+1 (same head)
    int h = lane >> 4;        // head = c0>>5
    float2 xv = *(const float2*)&x[(size_t)d * HID + c0];
    float rel0 = 0.f, rel1 = 0.f;
    for (int rr = 0; rr < nrel; ++rr) {
        const RelArg& R = (rr == 0) ? r0 : (rr == 1) ? r1 : r2;
        int base = R.off[d];
        int dg = R.deg[d];
        float aldh = R.ald[d * NHEAD + h];
        const __hip_bfloat16* hp = R.hs + R.hoff + c0;
        const int hstr = R.hstride;
        const int* ap = R.adj + base;
        float acc0 = 0.f, acc1 = 0.f, den = 0.f;
        int k = 0;
        for (; k + 4 <= dg; k += 4) {
            int s0 = ap[k], s1 = ap[k + 1], s2 = ap[k + 2], s3 = ap[k + 3];
            float w0 = __expf(lrelu(R.als[s0 * NHEAD + h] + aldh));
            float w1 = __expf(lrelu(R.als[s1 * NHEAD + h] + aldh));
            float w2 = __expf(lrelu(R.als[s2 * NHEAD + h] + aldh));
            float w3 = __expf(lrelu(R.als[s3 * NHEAD + h] + aldh));
            __hip_bfloat162 v0 = *(const __hip_bfloat162*)(hp + (size_t)s0 * hstr);
            __hip_bfloat162 v1 = *(const __hip_bfloat162*)(hp + (size_t)s1 * hstr);
            __hip_bfloat162 v2 = *(const __hip_bfloat162*)(hp + (size_t)s2 * hstr);
            __hip_bfloat162 v3 = *(const __hip_bfloat162*)(hp + (size_t)s3 * hstr);
            acc0 += w0 * __bfloat162float(v0.x) + w1 * __bfloat162float(v1.x)
                  + w2 * __bfloat162float(v2.x) + w3 * __bfloat162float(v3.x);
            acc1 += w0 * __bfloat162float(v0.y) + w1 * __bfloat162float(v1.y)
                  + w2 * __bfloat162float(v2.y) + w3 * __bfloat162float(v3.y);
            den += w0 + w1 + w2 + w3;
        }
        for (; k < dg; ++k) {
            int s = ap[k];
            float w = __expf(lrelu(R.als[s * NHEAD + h] + aldh));
            __hip_bfloat162 v = *(const __hip_bfloat162*)(hp + (size_t)s * hstr);
            acc0 += w * __bfloat162float(v.x);
            acc1 += w * __bfloat162float(v.y);
            den += w;
        }
        float inv = 1.f / (den + 1e-16f);
        rel0 += acc0 * inv + R.bias[c0];
        rel1 += acc1 * inv + R.bias[c0 + 1];
    }
    float v0 = rel0 * inv_nrel;
    float v1 = rel1 * inv_nrel;
    v0 = (v0 > 0.f) ? v0 : 0.f;
    v1 = (v1 > 0.f) ? v1 : 0.f;
    v0 += xv.x;
    v1 += xv.y;
    // wave-local LayerNorm over 128 channels (butterfly, no LDS)
    float s = v0 + v1, ss = v0 * v0 + v1 * v1;
#pragma unroll
    for (int o = 32; o; o >>= 1) {
        s += __shfl_xor(s, o);
        ss += __shfl_xor(ss, o);
    }
    float mu = s * (1.f / HID);
    float var = ss * (1.f / HID) - mu * mu;
    float rstd = rsqrtf(var + 1e-5f);
    float o0 = (v0 - mu) * rstd * ln_s[c0] + ln_b[c0];
    float o1 = (v1 - mu) * rstd * ln_s[c0 + 1] + ln_b[c0 + 1];
    *(float2*)&x[(size_t)d * HID + c0] = make_float2(o0, o1);
    __hip_bfloat162 ob;
    ob.x = __float2bfloat16(o0);
    ob.y = __float2bfloat16(o1);
    *(__hip_bfloat162*)&xb[(size_t)d * HID + c0] = ob;
}

// ---------------- pooling: small chunks (32 rows) -> high block count, few atomics ----------------
__global__ void k_pool_part(const float* __restrict__ x, const int* __restrict__ b,
                            int N, int toff, float* __restrict__ out) {
    int r0 = blockIdx.x * PCHUNK;
    if (r0 >= N) return;
    int rend = min(r0 + PCHUNK, N);
    int c = threadIdx.x; // 128
    int cur = b[r0];
    float acc = 0.f;
    for (int i = r0; i < rend; ++i) {
        int g = b[i];
        if (g != cur) {
            atomicAdd(&out[cur * 512 + toff + c], acc);
            acc = 0.f;
            cur = g;
        }
        acc += x[(size_t)i * HID + c];
    }
    atomicAdd(&out[cur * 512 + toff + c], acc);
}
__global__ void k_cnt(const int* __restrict__ b0, const int* __restrict__ b1,
                      const int* __restrict__ b2, const int* __restrict__ b3,
                      int N0, int N1, int N2, int N3, float* __restrict__ cnt) {
    int i = blockIdx.x * blockDim.x + threadIdx.x;
    if (i >= 256) return;
    int t = i >> 6, g = i & 63;
    const int* b = (t == 0) ? b0 : (t == 1) ? b1 : (t == 2) ? b2 : b3;
    int N = (t == 0) ? N0 : (t == 1) ? N1 : (t == 2) ? N2 : N3;
    int lo = 0, hi = N;
    while (lo < hi) { int m = (lo + hi) >> 1; if (b[m] < g) lo = m + 1; else hi = m; }
    int s = lo;
    hi = N;
    while (lo < hi) { int m = (lo + hi) >> 1; if (b[m] < g + 1) lo = m + 1; else hi = m; }
    cnt[i] = (float)(lo - s);
}
__global__ void k_div(float* __restrict__ out, const float* __restrict__ cnt) {
    int idx = blockIdx.x * blockDim.x + threadIdx.x;
    if (idx >= NGRAPH * 512) return;
    int g = idx >> 9, c = idx & 511, t = c >> 7;
    out[idx] = out[idx] / fmaxf(cnt[t * NGRAPH + g], 1.0f);
}

extern "C" void kernel_launch(void* const* d_in, const int* in_sizes, int n_in,
                              void* d_out, int out_size, void* d_ws, size_t ws_size,
                              hipStream_t stream) {
    const float* x_in[4] = {(const float*)d_in[0], (const float*)d_in[1],
                            (const float*)d_in[2], (const float*)d_in[3]};
    const float* Wp[4] = {(const float*)d_in[4], (const float*)d_in[6],
                          (const float*)d_in[8], (const float*)d_in[10]};
    const float* bp[4] = {(const float*)d_in[5], (const float*)d_in[7],
                          (const float*)d_in[9], (const float*)d_in[11]};
    const float* gat_W  = (const float*)d_in[12];
    const float* gat_as = (const float*)d_in[13];
    const float* gat_ad = (const float*)d_in[14];
    const float* gat_b  = (const float*)d_in[15];
    const float* ln_s   = (const float*)d_in[16];
    const float* ln_b   = (const float*)d_in[17];
    const int* esrc[8] = {(const int*)d_in[18], (const int*)d_in[20], (const int*)d_in[22],
                          (const int*)d_in[24], (const int*)d_in[26], (const int*)d_in[28],
                          (const int*)d_in[30], (const int*)d_in[32]};
    const int* edst[8] = {(const int*)d_in[19], (const int*)d_in[21], (const int*)d_in[23],
                          (const int*)d_in[25], (const int*)d_in[27], (const int*)d_in[29],
                          (const int*)d_in[31], (const int*)d_in[33]};
    const int* bidx[4] = {(const int*)d_in[34], (const int*)d_in[35],
                          (const int*)d_in[36], (const int*)d_in[37]};
    int E[8];
    {
        const int eidx[8] = {18, 20, 22, 24, 26, 28, 30, 32};
        for (int r = 0; r < 8; ++r) E[r] = in_sizes[eidx[r]];
    }
    const int Kin[4] = {8, 10, 7, 3};
    int N[4];
    for (int t = 0; t < 4; ++t) N[t] = in_sizes[t] / Kin[t];
    const int rel_st[8] = {0, 1, 0, 2, 0, 0, 1, 2};
    const int rel_dt[8] = {1, 0, 2, 0, 3, 0, 3, 3};
    const int rel_hoff[8] = {0, 0, 128, 0, 256, 384, 128, 128};
    const int grp_stride[4] = {512, 256, 256, 0};
    (void)ws_size; (void)n_in;

    // ---- workspace carve-up ----
    char* wbase = (char*)d_ws;
    size_t cur = 0;
    auto alloc = [&](size_t bytes) -> void* {
        void* p = wbase + cur;
        cur += (bytes + 15) & ~(size_t)15;
        return p;
    };
    float* x[4];
    __hip_bfloat16* xb[4];
    for (int t = 0; t < 4; ++t) x[t] = (float*)alloc((size_t)N[t] * HID * 4);
    for (int t = 0; t < 4; ++t) xb[t] = (__hip_bfloat16*)alloc((size_t)N[t] * HID * 2);
    __hip_bfloat16* hs_g[3];
    hs_g[0] = (__hip_bfloat16*)alloc((size_t)N[0] * 512 * 2);
    hs_g[1] = (__hip_bfloat16*)alloc((size_t)N[1] * 256 * 2);
    hs_g[2] = (__hip_bfloat16*)alloc((size_t)N[2] * 256 * 2);
    __hip_bfloat16* Wsw = (__hip_bfloat16*)alloc((size_t)2 * 131072 * 2);
    float* vecall = (float*)alloc((size_t)2 * 16 * 512 * 4);
    float *als_[8], *ald_[8];
    int *deg[8], *offs[8], *curs[8], *adj[8];
    for (int r = 0; r < 8; ++r) {
        int Ns = N[rel_st[r]], Nd = N[rel_dt[r]];
        als_[r] = (float*)alloc((size_t)Ns * NHEAD * 4);
        ald_[r] = (float*)alloc((size_t)Nd * NHEAD * 4);
        deg[r]  = (int*)alloc((size_t)Nd * 4);
        offs[r] = (int*)alloc((size_t)Nd * 4);
        curs[r] = (int*)alloc((size_t)Nd * 4);
        adj[r]  = (int*)alloc((size_t)E[r] * 4);
    }
    int* part   = (int*)alloc(512 * 4);
    float* cntf = (float*)alloc(256 * 4);

    // ---- 0. CSR build + weight prep ----
    for (int r = 0; r < 8; ++r) {
        int Nd = N[rel_dt[r]];
        int nparts = (Nd + 255) / 256;
        hipMemsetAsync(deg[r], 0, (size_t)Nd * 4, stream);
        k_hist<<<(E[r] + 255) / 256, 256, 0, stream>>>(edst[r], deg[r], E[r]);
        k_scan_part<<<nparts, 256, 0, stream>>>(deg[r], part, Nd);
        k_scan_top<<<1, 512, 0, stream>>>(part, nparts);
        k_scan_down<<<nparts, 256, 0, stream>>>(deg[r], part, offs[r], curs[r], Nd);
        k_scatter<<<(E[r] + 255) / 256, 256, 0, stream>>>(esrc[r], edst[r], curs[r], adj[r], E[r]);
    }
    k_castW<<<(262144 + 255) / 256, 256, 0, stream>>>(gat_W, Wsw);
    k_mkvec<<<(16384 + 255) / 256, 256, 0, stream>>>(gat_W, gat_as, gat_ad, vecall);

    // ---- 1. input projections ----
    for (int t = 0; t < 4; ++t)
        k_proj<<<(N[t] * HID + 255) / 256, 256, 0, stream>>>(x_in[t], Wp[t], bp[t], x[t], xb[t], N[t], Kin[t]);

    // ---- 2. layers ----
    const size_t g_off[3] = {0, 65536, 98304};
    const int g_ncols[3] = {512, 256, 256};
    for (int l = 0; l < 2; ++l) {
        for (int g = 0; g < 3; ++g) {
            dim3 grid((N[g] + 63) / 64, g_ncols[g] / 128);
            k_gemm<<<grid, 256, 0, stream>>>(xb[g], Wsw + (size_t)l * 131072 + g_off[g],
                                             hs_g[g], N[g], g_ncols[g]);
        }
        const float* vl = vecall + (size_t)l * 16 * 512;
        auto vvec = [&](int r, int side) { return vl + (size_t)(r * 2 + side) * 512; };
        {
            LogitPack P{};
            P.vec[0] = vvec(0, 0); P.out[0] = als_[0];
            P.vec[1] = vvec(2, 0); P.out[1] = als_[2];
            P.vec[2] = vvec(4, 0); P.out[2] = als_[4];
            P.vec[3] = vvec(5, 0); P.out[3] = als_[5];
            P.vec[4] = vvec(1, 1); P.out[4] = ald_[1];
            P.vec[5] = vvec(3, 1); P.out[5] = ald_[3];
            P.vec[6] = vvec(5, 1); P.out[6] = ald_[5];
            k_logits<7><<<(N[0] + 63) / 64, 256, 0, stream>>>(x[0], N[0], P);
        }
        {
            LogitPack P{};
            P.vec[0] = vvec(1, 0); P.out[0] = als_[1];
            P.vec[1] = vvec(6, 0); P.out[1] = als_[6];
            P.vec[2] = vvec(0, 1); P.out[2] = ald_[0];
            k_logits<3><<<(N[1] + 63) / 64, 256, 0, stream>>>(x[1], N[1], P);
        }
        {
            LogitPack P{};
            P.vec[0] = vvec(3, 0); P.out[0] = als_[3];
            P.vec[1] = vvec(7, 0); P.out[1] = als_[7];
            P.vec[2] = vvec(2, 1); P.out[2] = ald_[2];
            k_logits<3><<<(N[2] + 63) / 64, 256, 0, stream>>>(x[2], N[2], P);
        }
        {
            LogitPack P{};
            P.vec[0] = vvec(4, 1); P.out[0] = ald_[4];
            P.vec[1] = vvec(6, 1); P.out[1] = ald_[6];
            P.vec[2] = vvec(7, 1); P.out[2] = ald_[7];
            k_logits<3><<<(N[3] + 63) / 64, 256, 0, stream>>>(x[3], N[3], P);
        }
        auto mk = [&](int r) {
            RelArg a;
            int st = rel_st[r];
            a.hs = hs_g[st]; a.hstride = grp_stride[st]; a.hoff = rel_hoff[r];
            a.als = als_[r]; a.ald = ald_[r];
            a.adj = adj[r]; a.off = offs[r]; a.deg = deg[r];
            a.bias = gat_b + (size_t)(l * 8 + r) * HID;
            return a;
        };
        const float* ls = ln_s + l * HID;
        const float* lb = ln_b + l * HID;
        k_dst<<<(N[0] + 3) / 4, 256, 0, stream>>>(mk(1), mk(3), mk(5), 3, 1.f / 3.f, x[0], xb[0], ls, lb, N[0]);
        k_dst<<<(N[1] + 3) / 4, 256, 0, stream>>>(mk(0), mk(0), mk(0), 1, 1.f, x[1], xb[1], ls, lb, N[1]);
        k_dst<<<(N[2] + 3) / 4, 256, 0, stream>>>(mk(2), mk(2), mk(2), 1, 1.f, x[2], xb[2], ls, lb, N[2]);
        k_dst<<<(N[3] + 3) / 4, 256, 0, stream>>>(mk(4), mk(6), mk(7), 3, 1.f / 3.f, x[3], xb[3], ls, lb, N[3]);
    }

    // ---- 3. pooling ----
    hipMemsetAsync(d_out, 0, (size_t)out_size * 4, stream);
    k_cnt<<<1, 256, 0, stream>>>(bidx[0], bidx[1], bidx[2], bidx[3],
                                 N[0], N[1], N[2], N[3], cntf);
    for (int t = 0; t < 4; ++t)
        k_pool_part<<<(N[t] + PCHUNK - 1) / PCHUNK, 128, 0, stream>>>(x[t], bidx[t], N[t], t * HID, (float*)d_out);
    k_div<<<(NGRAPH * 512 + 255) / 256, 256, 0, stream>>>((float*)d_out, cntf);
}